// Round 10
// baseline (161.907 us; speedup 1.0000x reference)
//
#include <hip/hip_runtime.h>
#include <hip/hip_bf16.h>
#include <math.h>

static constexpr int Bc = 2, Tc = 2048, Cc = 1024, Hc = 16;
static constexpr int Mc = Bc * Tc;  // 4096 rows
static constexpr int NCc = 32, Lc = 64;  // chunks per (b,h), chunk length
static constexpr int TP = 72;  // LDS tile pitch (shorts) for scan kernels

typedef __attribute__((ext_vector_type(8))) short bf16x8;
typedef __attribute__((ext_vector_type(4))) float f32x4;

// ---------- dtype helpers ----------
__device__ __forceinline__ float bf2f(unsigned short u) {
  return __uint_as_float((unsigned)u << 16);
}
__device__ __forceinline__ unsigned short f2bf(float f) {
  __hip_bfloat16 h = __float2bfloat16(f);
  return *(unsigned short*)&h;
}
__device__ __forceinline__ float4 ld4(const float* p) { return *(const float4*)p; }
__device__ __forceinline__ float4 ld4(const unsigned short* p) {
  ushort4 u = *(const ushort4*)p;
  return make_float4(bf2f(u.x), bf2f(u.y), bf2f(u.z), bf2f(u.w));
}
__device__ __forceinline__ void stv(float* p, float v) { *p = v; }
__device__ __forceinline__ void stv(unsigned short* p, float v) { *p = f2bf(v); }

__device__ __forceinline__ void glds16(const unsigned short* src, unsigned short* dst) {
  __builtin_amdgcn_global_load_lds(
      (const __attribute__((address_space(1))) unsigned int*)src,
      (__attribute__((address_space(3))) unsigned int*)dst, 16, 0, 0);
}

// ---------------- RoPE tables ----------------
__global__ __launch_bounds__(256) void k_tables(float* __restrict__ tc, float* __restrict__ ts) {
  int i = blockIdx.x * 256 + threadIdx.x;       // < Tc*32
  int t = i >> 5, f = i & 31;
  float ivf = 1.0f / powf(10000.f, (float)f / 32.f);
  float fr = (float)t * ivf;
  tc[i] = cosf(fr);
  ts[i] = sinf(fr);
}

__device__ __forceinline__ float phi_fn(float x) { return x > 0.f ? x + 1.f : __expf(x); }

// ---------------- W[K][N] fp32 -> WT[N][K] bf16, 4 weights via blockIdx.z ----------------
__global__ __launch_bounds__(256) void k_trans(
    const float* __restrict__ w0, const float* __restrict__ w1,
    const float* __restrict__ w2, const float* __restrict__ w3,
    unsigned short* __restrict__ o0, unsigned short* __restrict__ o1,
    unsigned short* __restrict__ o2, unsigned short* __restrict__ o3) {
  const float* W = (blockIdx.z == 0) ? w0 : (blockIdx.z == 1) ? w1 : (blockIdx.z == 2) ? w2 : w3;
  unsigned short* O = (blockIdx.z == 0) ? o0 : (blockIdx.z == 1) ? o1 : (blockIdx.z == 2) ? o2 : o3;
  __shared__ float tile[32][33];
  int k0 = blockIdx.x * 32, n0 = blockIdx.y * 32;
  int t = threadIdx.x;
  int kk = t >> 3, nn4 = (t & 7) * 4;
  float4 v = *(const float4*)&W[(size_t)(k0 + kk) * Cc + n0 + nn4];
  tile[kk][nn4] = v.x; tile[kk][nn4 + 1] = v.y; tile[kk][nn4 + 2] = v.z; tile[kk][nn4 + 3] = v.w;
  __syncthreads();
  int nn = t >> 3, kk4 = (t & 7) * 4;
  ushort4 o = make_ushort4(f2bf(tile[kk4][nn]), f2bf(tile[kk4 + 1][nn]),
                           f2bf(tile[kk4 + 2][nn]), f2bf(tile[kk4 + 3][nn]));
  *(ushort4*)&O[(size_t)(n0 + nn) * Cc + k0 + kk4] = o;
}

// ================ pipelined MFMA GEMM core (counted-vmcnt, 3-buffer) ================
// A[M][K], BT[N][K] bf16 row-major, K=Cc. Tile BM=32*FM x BN=32*FN, BK=32.
// 4 waves (2x2); wave tile (16*FM)x(16*FN). global_load_lds staging into 3 LDS
// buffers; raw s_barrier + s_waitcnt vmcnt(NL) (never 0 mid-loop) keeps 1 tile in flight.
// Source-side XOR swizzle blk^=(row>>1)&3, matched on ds_read.
template <int FM, int FN>
__device__ __forceinline__ void stage_tiles(const unsigned short* __restrict__ A,
    const unsigned short* __restrict__ BT, unsigned short* As, unsigned short* Bs,
    int buf, int kt, int m0, int n0, int w, int l) {
  constexpr int BM = 32 * FM, BN = 32 * FN;
  const int srow = l >> 2, sblk = l & 3;
  const int k0 = kt * 32;
#pragma unroll
  for (int i = w; i < BM / 16; i += 4) {
    int row = i * 16 + srow;
    int blk = sblk ^ ((row >> 1) & 3);
    glds16(A + (size_t)(m0 + row) * Cc + k0 + blk * 8, As + buf * (BM * 32) + i * 512);
  }
#pragma unroll
  for (int i = w; i < BN / 16; i += 4) {
    int row = i * 16 + srow;
    int blk = sblk ^ ((row >> 1) & 3);
    glds16(BT + (size_t)(n0 + row) * Cc + k0 + blk * 8, Bs + buf * (BN * 32) + i * 512);
  }
}

template <int FM, int FN>
__device__ __forceinline__ void gemm_loop(const unsigned short* __restrict__ A,
    const unsigned short* __restrict__ BT,
    unsigned short* As, unsigned short* Bs, f32x4 (&acc)[FM][FN],
    int m0, int n0, int w, int l) {
  constexpr int BM = 32 * FM, BN = 32 * FN;
  constexpr int NT = Cc / 32;
  constexpr int NL = (BM + BN) / 64;   // glds16 per wave per stage
  const int wr = w >> 1, wc = w & 1;
  const int lrow = l & 15, lb = l >> 4;

  // prologue: tiles 0,1 into buffers 0,1
  stage_tiles<FM, FN>(A, BT, As, Bs, 0, 0, m0, n0, w, l);
  stage_tiles<FM, FN>(A, BT, As, Bs, 1, 1, m0, n0, w, l);

  int cur = 0, pre = 2;  // pre = (t+2)%3
  for (int t = 0; t < NT; ++t) {
    if (t + 1 < NT) {
      if constexpr (NL == 6) asm volatile("s_waitcnt vmcnt(6)" ::: "memory");
      else if constexpr (NL == 4) asm volatile("s_waitcnt vmcnt(4)" ::: "memory");
      else if constexpr (NL == 3) asm volatile("s_waitcnt vmcnt(3)" ::: "memory");
      else asm volatile("s_waitcnt vmcnt(0)" ::: "memory");
    } else {
      asm volatile("s_waitcnt vmcnt(0)" ::: "memory");
    }
    __builtin_amdgcn_s_barrier();
    if (t + 2 < NT) stage_tiles<FM, FN>(A, BT, As, Bs, pre, t + 2, m0, n0, w, l);

    const unsigned short* Ab = As + cur * (BM * 32);
    const unsigned short* Bb = Bs + cur * (BN * 32);
    bf16x8 bf[FN];
#pragma unroll
    for (int fn = 0; fn < FN; ++fn) {
      int row = wc * 16 * FN + fn * 16 + lrow;
      bf[fn] = *(const bf16x8*)&Bb[row * 32 + ((lb ^ ((row >> 1) & 3)) * 8)];
    }
    // fm in halves of <=4 to bound live operand registers (FM=8 case)
#pragma unroll
    for (int fh = 0; fh < FM; fh += 4) {
      constexpr int FH = (FM < 4) ? FM : 4;
      bf16x8 af[FH];
#pragma unroll
      for (int fi = 0; fi < FH; ++fi) {
        int row = wr * 16 * FM + (fh + fi) * 16 + lrow;
        af[fi] = *(const bf16x8*)&Ab[row * 32 + ((lb ^ ((row >> 1) & 3)) * 8)];
      }
#pragma unroll
      for (int fi = 0; fi < FH; ++fi)
#pragma unroll
        for (int fn = 0; fn < FN; ++fn)
          acc[fh + fi][fn] = __builtin_amdgcn_mfma_f32_16x16x32_bf16(af[fi], bf[fn], acc[fh + fi][fn], 0, 0, 0);
    }
    cur = (cur == 2) ? 0 : cur + 1;
    pre = (pre == 2) ? 0 : pre + 1;
  }
}

// ---------------- fused Q/K/V projections (blockIdx.z selects); 256x128 tile ----------------
__global__ __launch_bounds__(256) void k_qkv(const unsigned short* __restrict__ xbf,
    const unsigned short* __restrict__ qwT, const unsigned short* __restrict__ kwT,
    const unsigned short* __restrict__ vwT,
    unsigned short* __restrict__ Qo, unsigned short* __restrict__ Ko, unsigned short* __restrict__ Vo,
    const float* __restrict__ tabC, const float* __restrict__ tabS) {
  __shared__ unsigned short As[3 * 256 * 32];
  __shared__ unsigned short Bs[3 * 128 * 32];
  const int zz = blockIdx.z;
  const unsigned short* BT = (zz == 0) ? qwT : (zz == 1) ? kwT : vwT;
  unsigned short* Co = (zz == 0) ? Qo : (zz == 1) ? Ko : Vo;
  const int tid = threadIdx.x;
  const int l = tid & 63, w = tid >> 6;
  const int n0 = blockIdx.x * 128, m0 = blockIdx.y * 256;

  f32x4 acc[8][4];
#pragma unroll
  for (int i = 0; i < 8; ++i)
#pragma unroll
    for (int j = 0; j < 4; ++j) acc[i][j] = (f32x4){0.f, 0.f, 0.f, 0.f};

  gemm_loop<8, 4>(xbf, BT, As, Bs, acc, m0, n0, w, l);

  const int wr = w >> 1, wc = w & 1;
#pragma unroll
  for (int fm = 0; fm < 8; ++fm) {
#pragma unroll
    for (int fn = 0; fn < 4; ++fn) {
#pragma unroll
      for (int r = 0; r < 4; ++r) {
        float v = acc[fm][fn][r];
        int row = m0 + wr * 128 + fm * 16 + (l >> 4) * 4 + r;
        int col = n0 + wc * 64 + fn * 16 + (l & 15);
        if (zz < 2) {
          float p = __shfl_xor(v, 1);
          int t = row & (Tc - 1);
          int pi = (col & 63) >> 1;
          float cv = tabC[t * 32 + pi], sv = tabS[t * 32 + pi];
          float res = (col & 1) ? (p * sv + v * cv) : (v * cv - p * sv);
          Co[(size_t)row * Cc + col] = f2bf(phi_fn(res));
        } else {
          Co[(size_t)row * Cc + col] = f2bf(v);
        }
      }
    }
  }
}

// ---------------- out-proj: 64x128 tile, +bias +residual -> fp32 ----------------
__global__ __launch_bounds__(256) void k_oproj(const unsigned short* __restrict__ Ybf,
    const unsigned short* __restrict__ owT, float* __restrict__ Co,
    const float* __restrict__ bias, const float* __restrict__ resid) {
  __shared__ unsigned short As[3 * 64 * 32];
  __shared__ unsigned short Bs[3 * 128 * 32];
  const int tid = threadIdx.x;
  const int l = tid & 63, w = tid >> 6;
  const int n0 = blockIdx.x * 128, m0 = blockIdx.y * 64;

  f32x4 acc[2][4];
#pragma unroll
  for (int i = 0; i < 2; ++i)
#pragma unroll
    for (int j = 0; j < 4; ++j) acc[i][j] = (f32x4){0.f, 0.f, 0.f, 0.f};

  gemm_loop<2, 4>(Ybf, owT, As, Bs, acc, m0, n0, w, l);

  const int wr = w >> 1, wc = w & 1;
#pragma unroll
  for (int fm = 0; fm < 2; ++fm) {
#pragma unroll
    for (int fn = 0; fn < 4; ++fn) {
#pragma unroll
      for (int r = 0; r < 4; ++r) {
        int row = m0 + wr * 32 + fm * 16 + (l >> 4) * 4 + r;
        int col = n0 + wc * 64 + fn * 16 + (l & 15);
        Co[(size_t)row * Cc + col] = acc[fm][fn][r] + bias[col] + resid[(size_t)row * Cc + col];
      }
    }
  }
}

// ---------------- legacy fp32 SIMT GEMM (fallback path only) ----------------
template <typename AT, typename OT, int MODE>
__global__ __launch_bounds__(256) void k_gemm128(
    const AT* __restrict__ A, const float* __restrict__ Bw, OT* __restrict__ Co,
    int M, int N, int K,
    const float* __restrict__ tabC, const float* __restrict__ tabS,
    const float* __restrict__ bias, const float* __restrict__ resid) {
  __shared__ float As[16][132];
  __shared__ float Bs[16][132];
  const int tid = threadIdx.x;
  const int tx = tid & 15, ty = tid >> 4;
  const int n0 = blockIdx.x * 128, m0 = blockIdx.y * 128;
  float acc[8][8];
#pragma unroll
  for (int i = 0; i < 8; ++i)
#pragma unroll
    for (int j = 0; j < 8; ++j) acc[i][j] = 0.f;
  for (int k0 = 0; k0 < K; k0 += 16) {
#pragma unroll
    for (int rep = 0; rep < 2; ++rep) {
      int lin = tid + rep * 256;
      int r = lin >> 2, c4 = (lin & 3) << 2;
      float4 av = ld4(&A[(size_t)(m0 + r) * K + k0 + c4]);
      As[c4 + 0][r] = av.x; As[c4 + 1][r] = av.y;
      As[c4 + 2][r] = av.z; As[c4 + 3][r] = av.w;
      int rb = lin >> 5, cb = (lin & 31) << 2;
      *(float4*)&Bs[rb][cb] = *(const float4*)&Bw[(size_t)(k0 + rb) * N + n0 + cb];
    }
    __syncthreads();
#pragma unroll
    for (int kk = 0; kk < 16; ++kk) {
      float4 a0 = *(const float4*)&As[kk][ty * 8];
      float4 a1 = *(const float4*)&As[kk][ty * 8 + 4];
      float4 b0 = *(const float4*)&Bs[kk][tx * 8];
      float4 b1 = *(const float4*)&Bs[kk][tx * 8 + 4];
      float avv[8] = {a0.x, a0.y, a0.z, a0.w, a1.x, a1.y, a1.z, a1.w};
      float bvv[8] = {b0.x, b0.y, b0.z, b0.w, b1.x, b1.y, b1.z, b1.w};
#pragma unroll
      for (int i = 0; i < 8; ++i)
#pragma unroll
        for (int j = 0; j < 8; ++j) acc[i][j] = fmaf(avv[i], bvv[j], acc[i][j]);
    }
    __syncthreads();
  }
  if constexpr (MODE == 1) {
#pragma unroll
    for (int i = 0; i < 8; ++i) {
      int row = m0 + ty * 8 + i;
      int t = row & (Tc - 1);
#pragma unroll
      for (int j = 0; j < 8; j += 2) {
        int col = n0 + tx * 8 + j;
        int pi = (col & 63) >> 1;
        float cv = tabC[t * 32 + pi], sv = tabS[t * 32 + pi];
        float xe = acc[i][j], xo = acc[i][j + 1];
        stv(&Co[(size_t)row * N + col], phi_fn(xe * cv - xo * sv));
        stv(&Co[(size_t)row * N + col + 1], phi_fn(xe * sv + xo * cv));
      }
    }
  } else if constexpr (MODE == 2) {
#pragma unroll
    for (int i = 0; i < 8; ++i) {
      int row = m0 + ty * 8 + i;
#pragma unroll
      for (int j = 0; j < 8; ++j) {
        int col = n0 + tx * 8 + j;
        stv(&Co[(size_t)row * N + col], acc[i][j] + bias[col] + resid[(size_t)row * N + col]);
      }
    }
  } else {
#pragma unroll
    for (int i = 0; i < 8; ++i) {
      int row = m0 + ty * 8 + i;
#pragma unroll
      for (int j = 0; j < 8; ++j) {
        int col = n0 + tx * 8 + j;
        stv(&Co[(size_t)row * N + col], acc[i][j]);
      }
    }
  }
}

// ---------------- gate/decay projections (writes RATE) + fused x->bf16 ----------------
__global__ __launch_bounds__(256) void k_small(
    const float* __restrict__ x, const float* __restrict__ gate_w, const float* __restrict__ gate_b,
    const float* __restrict__ decay_w, const float* __restrict__ decay_b,
    const float* __restrict__ decay_w0, float* __restrict__ gate_o, float* __restrict__ rate_o,
    unsigned short* __restrict__ xbf_o) {
  __shared__ float xs[1024];
  __shared__ float part[8][32];
  int bt = blockIdx.x;
  int tid = threadIdx.x;
  float4 xv = *(const float4*)&x[(size_t)bt * Cc + tid * 4];
  *(float4*)&xs[tid * 4] = xv;
  if (xbf_o) {
    ushort4 u = make_ushort4(f2bf(xv.x), f2bf(xv.y), f2bf(xv.z), f2bf(xv.w));
    *(ushort4*)&xbf_o[(size_t)bt * Cc + tid * 4] = u;
  }
  __syncthreads();
  int o = tid & 31, seg = tid >> 5;
  const float* wp = (o < 16) ? gate_w : decay_w;
  int oc = o & 15;
  float p = 0.f;
  int kb = seg * 128;
#pragma unroll 4
  for (int kk = 0; kk < 128; ++kk) {
    int k = kb + kk;
    p = fmaf(xs[k], wp[(size_t)k * 16 + oc], p);
  }
  part[seg][o] = p;
  __syncthreads();
  if (tid < 32) {
    float s = 0.f;
#pragma unroll
    for (int sg = 0; sg < 8; ++sg) s += part[sg][tid];
    int b = bt >> 11, t = bt & (Tc - 1);
    if (tid < 16) {
      float gv = 1.f / (1.f + expf(-(s + gate_b[tid])));
      gate_o[((size_t)(b * Hc + tid)) * Tc + t] = gv;
    } else {
      int hh = tid - 16;
      float raw = s + decay_b[hh] + decay_w0[hh];
      float sp = raw > 20.f ? raw : log1pf(expf(raw));
      float rate = fminf(fmaxf(sp, 1e-4f), 10.f);
      rate_o[((size_t)(b * Hc + hh)) * Tc + t] = rate;
    }
  }
}

// ---------------- Phase A (MFMA): per-chunk summaries S^T[e][d], Dsum[d], P ----------------
__global__ __launch_bounds__(256) void k_scanA2(
    const unsigned short* __restrict__ Kb, const unsigned short* __restrict__ Vb,
    const float* __restrict__ rateB, const float* __restrict__ gateB,
    unsigned short* __restrict__ S, float* __restrict__ Dsum, float* __restrict__ Pbuf) {
  int blk = blockIdx.x;
  int bh = blk >> 5, c = blk & 31;
  int b = bh >> 4, h = bh & 15;
  int tid = threadIdx.x;
  int l = tid & 63, wv = tid >> 6;
  __shared__ unsigned short KT[64 * TP];   // [d][s]
  __shared__ unsigned short VT[64 * TP];   // [e][s], scaled by w_s
  __shared__ float Rc[64], gs[64], ws[64];
  size_t base = ((size_t)b * Tc + (size_t)c * 64) * Cc + h * 64;
  {
    int s = tid >> 2, d0g = (tid & 3) * 16;
    const unsigned short* kr = Kb + base + (size_t)s * Cc + d0g;
    unsigned short kv[16];
    *(uint4*)kv = *(const uint4*)kr; *(uint4*)(kv + 8) = *(const uint4*)(kr + 8);
#pragma unroll
    for (int i = 0; i < 16; ++i) KT[(d0g + i) * TP + s] = kv[i];
  }
  if (wv == 0) {
    float r = rateB[(size_t)bh * Tc + c * 64 + l];
    float g = gateB[(size_t)bh * Tc + c * 64 + l];
    float v = r;
#pragma unroll
    for (int off = 1; off < 64; off <<= 1) { float u = __shfl_up(v, off); if (l >= off) v += u; }
    Rc[l] = v; gs[l] = g;
  }
  __syncthreads();
  float Rtot = Rc[63];
  if (wv == 0) ws[l] = __expf(Rc[l] - Rtot) * gs[l];
  __syncthreads();
  {
    int s = tid >> 2, e0g = (tid & 3) * 16;
    float wsv = ws[s];
    const unsigned short* vr = Vb + base + (size_t)s * Cc + e0g;
    unsigned short vvv[16];
    *(uint4*)vvv = *(const uint4*)vr; *(uint4*)(vvv + 8) = *(const uint4*)(vr + 8);
#pragma unroll
    for (int i = 0; i < 16; ++i) VT[(e0g + i) * TP + s] = f2bf(bf2f(vvv[i]) * wsv);
  }
  __syncthreads();
  f32x4 acc[4];
#pragma unroll
  for (int i = 0; i < 4; ++i) acc[i] = (f32x4){0.f, 0.f, 0.f, 0.f};
  const int lrow = l & 15, lk8 = (l >> 4) * 8;
#pragma unroll
  for (int ks = 0; ks < 2; ++ks) {
    bf16x8 a = *(const bf16x8*)&VT[(wv * 16 + lrow) * TP + ks * 32 + lk8];
#pragma unroll
    for (int fn = 0; fn < 4; ++fn) {
      bf16x8 bb = *(const bf16x8*)&KT[(fn * 16 + lrow) * TP + ks * 32 + lk8];
      acc[fn] = __builtin_amdgcn_mfma_f32_16x16x32_bf16(a, bb, acc[fn], 0, 0, 0);
    }
  }
  size_t sb = (size_t)blk * 4096;
#pragma unroll
  for (int fn = 0; fn < 4; ++fn)
#pragma unroll
    for (int r = 0; r < 4; ++r) {
      int e = wv * 16 + (l >> 4) * 4 + r;
      int d = fn * 16 + (l & 15);
      S[sb + e * 64 + d] = f2bf(acc[fn][r]);
    }
  if (tid < 64) {
    float s = 0.f;
#pragma unroll 8
    for (int ss = 0; ss < 64; ++ss) s += bf2f(KT[tid * TP + ss]) * ws[ss];
    Dsum[(size_t)blk * 64 + tid] = s;
  }
  if (tid == 0) Pbuf[blk] = __expf(-Rtot);
}

// ---------------- Phase B: serial carry across chunks (1-deep prefetch) ----------------
__global__ __launch_bounds__(256) void k_scanB(unsigned short* __restrict__ S, float* __restrict__ Dsum,
                                               const float* __restrict__ Pbuf) {
  int bh = blockIdx.x;
  int tid = threadIdx.x;
  float Nreg[16];
#pragma unroll
  for (int k = 0; k < 16; ++k) Nreg[k] = 0.f;
  float Dreg = 0.f;
  unsigned short curS[16]; float curD = 0.f, curP;
  {
    size_t sb = ((size_t)bh * NCc) * 4096;
#pragma unroll
    for (int k = 0; k < 16; ++k) curS[k] = S[sb + tid + k * 256];
    if (tid < 64) curD = Dsum[((size_t)bh * NCc) * 64 + tid];
    curP = Pbuf[bh * NCc];
  }
  for (int c = 0; c < NCc; ++c) {
    unsigned short nxtS[16]; float nxtD = 0.f, nxtP = 0.f;
    if (c + 1 < NCc) {
      size_t sb = ((size_t)bh * NCc + c + 1) * 4096;
#pragma unroll
      for (int k = 0; k < 16; ++k) nxtS[k] = S[sb + tid + k * 256];
      if (tid < 64) nxtD = Dsum[((size_t)bh * NCc + c + 1) * 64 + tid];
      nxtP = Pbuf[bh * NCc + c + 1];
    }
    size_t sb = ((size_t)bh * NCc + c) * 4096;
#pragma unroll
    for (int k = 0; k < 16; ++k) {
      float tmp = bf2f(curS[k]);
      S[sb + tid + k * 256] = f2bf(Nreg[k]);
      Nreg[k] = Nreg[k] * curP + tmp;
    }
    if (tid < 64) {
      size_t db = ((size_t)bh * NCc + c) * 64 + tid;
      float tmp = curD;
      Dsum[db] = Dreg;
      Dreg = Dreg * curP + tmp;
    }
#pragma unroll
    for (int k = 0; k < 16; ++k) curS[k] = nxtS[k];
    curD = nxtD; curP = nxtP;
  }
}

// ---------------- Phase C (MFMA): intra-chunk + start-state, full output ----------------
__global__ __launch_bounds__(256) void k_scanC2(
    const unsigned short* __restrict__ Qb, const unsigned short* __restrict__ Kb,
    const unsigned short* __restrict__ Vb,
    const float* __restrict__ rateB, const float* __restrict__ gateB,
    const unsigned short* __restrict__ S, const float* __restrict__ Dsum,
    unsigned short* __restrict__ Yb) {
  int blk = blockIdx.x;
  int bh = blk >> 5, c = blk & 31;
  int b = bh >> 4, h = bh & 15;
  int tid = threadIdx.x;
  int l = tid & 63, wv = tid >> 6;
  __shared__ unsigned short Qs[64 * TP];
  __shared__ unsigned short Ks[64 * TP];   // overlaid by W' after QK
  __shared__ unsigned short VT[64 * TP];
  __shared__ unsigned short Ss[64 * TP];
  __shared__ float Rc[64], gs[64], DstL[64];
  size_t base = ((size_t)b * Tc + (size_t)c * 64) * Cc + h * 64;
  {
    int rr = tid >> 2, c0 = (tid & 3) * 16;
    const unsigned short* qr = Qb + base + (size_t)rr * Cc + c0;
    const unsigned short* kr = Kb + base + (size_t)rr * Cc + c0;
    const unsigned short* vr = Vb + base + (size_t)rr * Cc + c0;
    const unsigned short* sr = S + (size_t)blk * 4096 + rr * 64 + c0;
    *(uint4*)&Qs[rr * TP + c0] = *(const uint4*)qr;
    *(uint4*)&Qs[rr * TP + c0 + 8] = *(const uint4*)(qr + 8);
    *(uint4*)&Ks[rr * TP + c0] = *(const uint4*)kr;
    *(uint4*)&Ks[rr * TP + c0 + 8] = *(const uint4*)(kr + 8);
    *(uint4*)&Ss[rr * TP + c0] = *(const uint4*)sr;
    *(uint4*)&Ss[rr * TP + c0 + 8] = *(const uint4*)(sr + 8);
    unsigned short vvv[16];
    *(uint4*)vvv = *(const uint4*)vr; *(uint4*)(vvv + 8) = *(const uint4*)(vr + 8);
#pragma unroll
    for (int i = 0; i < 16; ++i) VT[(c0 + i) * TP + rr] = vvv[i];
  }
  if (wv == 0) {
    float r = rateB[(size_t)bh * Tc + c * 64 + l];
    float g = gateB[(size_t)bh * Tc + c * 64 + l];
    float v = r;
#pragma unroll
    for (int off = 1; off < 64; off <<= 1) { float u = __shfl_up(v, off); if (l >= off) v += u; }
    Rc[l] = v; gs[l] = g;
    DstL[l] = Dsum[(size_t)blk * 64 + l];
  }
  __syncthreads();
  const int lrow = l & 15, lk8 = (l >> 4) * 8;
  f32x4 qk[4];
#pragma unroll
  for (int i = 0; i < 4; ++i) qk[i] = (f32x4){0.f, 0.f, 0.f, 0.f};
#pragma unroll
  for (int ks = 0; ks < 2; ++ks) {
    bf16x8 a = *(const bf16x8*)&Qs[(wv * 16 + lrow) * TP + ks * 32 + lk8];
#pragma unroll
    for (int fn = 0; fn < 4; ++fn) {
      bf16x8 bb = *(const bf16x8*)&Ks[(fn * 16 + lrow) * TP + ks * 32 + lk8];
      qk[fn] = __builtin_amdgcn_mfma_f32_16x16x32_bf16(a, bb, qk[fn], 0, 0, 0);
    }
  }
  __syncthreads();
  float deni[4] = {0.f, 0.f, 0.f, 0.f};
  float rct[4];
#pragma unroll
  for (int r = 0; r < 4; ++r) rct[r] = Rc[wv * 16 + (l >> 4) * 4 + r];
#pragma unroll
  for (int fn = 0; fn < 4; ++fn) {
    int s = fn * 16 + (l & 15);
    float rs = Rc[s], g = gs[s];
#pragma unroll
    for (int r = 0; r < 4; ++r) {
      int t = wv * 16 + (l >> 4) * 4 + r;
      float wgt = (s <= t) ? __expf(rs - rct[r]) * g : 0.f;
      unsigned short sb16 = f2bf(qk[fn][r] * wgt);
      deni[r] += bf2f(sb16);
      Ks[t * TP + s] = sb16;
    }
  }
#pragma unroll
  for (int r = 0; r < 4; ++r) {
    deni[r] += __shfl_xor(deni[r], 1);
    deni[r] += __shfl_xor(deni[r], 2);
    deni[r] += __shfl_xor(deni[r], 4);
    deni[r] += __shfl_xor(deni[r], 8);
  }
  f32x4 nm[4], nm2[4], dn2;
#pragma unroll
  for (int i = 0; i < 4; ++i) { nm[i] = (f32x4){0.f,0.f,0.f,0.f}; nm2[i] = (f32x4){0.f,0.f,0.f,0.f}; }
  dn2 = (f32x4){0.f, 0.f, 0.f, 0.f};
#pragma unroll
  for (int ks = 0; ks < 2; ++ks) {
    bf16x8 aw = *(const bf16x8*)&Ks[(wv * 16 + lrow) * TP + ks * 32 + lk8];
    bf16x8 aq = *(const bf16x8*)&Qs[(wv * 16 + lrow) * TP + ks * 32 + lk8];
#pragma unroll
    for (int fn = 0; fn < 4; ++fn) {
      bf16x8 bv = *(const bf16x8*)&VT[(fn * 16 + lrow) * TP + ks * 32 + lk8];
      bf16x8 bs = *(const bf16x8*)&Ss[(fn * 16 + lrow) * TP + ks * 32 + lk8];
      nm[fn] = __builtin_amdgcn_mfma_f32_16x16x32_bf16(aw, bv, nm[fn], 0, 0, 0);
      nm2[fn] = __builtin_amdgcn_mfma_f32_16x16x32_bf16(aq, bs, nm2[fn], 0, 0, 0);
    }
    bf16x8 bd = (bf16x8){0, 0, 0, 0, 0, 0, 0, 0};
    if (lrow == 0) {
#pragma unroll
      for (int i = 0; i < 8; ++i) bd[i] = (short)f2bf(DstL[ks * 32 + lk8 + i]);
    }
    dn2 = __builtin_amdgcn_mfma_f32_16x16x32_bf16(aq, bd, dn2, 0, 0, 0);
  }
  float den2v[4];
#pragma unroll
  for (int r = 0; r < 4; ++r) den2v[r] = __shfl(dn2[r], (l & 48));
#pragma unroll
  for (int r = 0; r < 4; ++r) {
    int t = wv * 16 + (l >> 4) * 4 + r;
    float at = __expf(-rct[r]);
    float dv = deni[r] + at * den2v[r] + 1e-6f;
#pragma unroll
    for (int fn = 0; fn < 4; ++fn) {
      int e = fn * 16 + (l & 15);
      float numv = nm[fn][r] + at * nm2[fn][r];
      Yb[base + (size_t)t * Cc + e] = f2bf(numv / dv);
    }
  }
}

// ---------------- legacy serial scan (fallback path only; rate input) ----------------
__device__ __forceinline__ void load16(const unsigned short* __restrict__ p, float* d) {
  uint4 u = *(const uint4*)p;
  uint4 v = *(const uint4*)(p + 8);
  d[0] = __uint_as_float(u.x << 16); d[1] = __uint_as_float(u.x & 0xFFFF0000u);
  d[2] = __uint_as_float(u.y << 16); d[3] = __uint_as_float(u.y & 0xFFFF0000u);
  d[4] = __uint_as_float(u.z << 16); d[5] = __uint_as_float(u.z & 0xFFFF0000u);
  d[6] = __uint_as_float(u.w << 16); d[7] = __uint_as_float(u.w & 0xFFFF0000u);
  d[8] = __uint_as_float(v.x << 16); d[9] = __uint_as_float(v.x & 0xFFFF0000u);
  d[10] = __uint_as_float(v.y << 16); d[11] = __uint_as_float(v.y & 0xFFFF0000u);
  d[12] = __uint_as_float(v.z << 16); d[13] = __uint_as_float(v.z & 0xFFFF0000u);
  d[14] = __uint_as_float(v.w << 16); d[15] = __uint_as_float(v.w & 0xFFFF0000u);
}

__global__ __launch_bounds__(256) void k_scan(const unsigned short* __restrict__ phiQ,
    const unsigned short* __restrict__ phiK, const unsigned short* __restrict__ Vb,
    const float* __restrict__ rateB, const float* __restrict__ gateB,
    unsigned short* __restrict__ Yb) {
  int bh = blockIdx.x;
  int b = bh >> 4, h = bh & 15;
  int tid = threadIdx.x;
  int w = tid >> 6, l = tid & 63;
  int e = (w << 4) | (l & 15);
  int d0 = (l >> 4) << 4;
  size_t base = ((size_t)b * Tc) * Cc + h * 64;
  const unsigned short* qp = phiQ + base + d0;
  const unsigned short* kp = phiK + base + d0;
  const unsigned short* vp = Vb + base + e;
  const float* bp = rateB + (size_t)bh * Tc;
  const float* gp = gateB + (size_t)bh * Tc;
  unsigned short* yp = Yb + base + e;
  float Ns[16], Ds[16];
#pragma unroll
  for (int j = 0; j < 16; ++j) { Ns[j] = 0.f; Ds[j] = 0.f; }
  const bool wr = (l < 16);
  for (int t = 0; t < Tc; ++t) {
    float q[16], k[16];
    load16(qp + (size_t)t * Cc, q);
    load16(kp + (size_t)t * Cc, k);
    float vv = bf2f(vp[(size_t)t * Cc]);
    float btv = __expf(-bp[t]), gtv = gp[t];
    float yn = 0.f, den = 0.f;
#pragma unroll
    for (int j = 0; j < 16; ++j) {
      float wj = k[j] * gtv;
      float ns = fmaf(Ns[j], btv, wj * vv);
      float ds = fmaf(Ds[j], btv, wj);
      Ns[j] = ns; Ds[j] = ds;
      yn = fmaf(q[j], ns, yn);
      den = fmaf(q[j], ds, den);
    }
    yn += __shfl_xor(yn, 16); yn += __shfl_xor(yn, 32);
    den += __shfl_xor(den, 16); den += __shfl_xor(den, 32);
    if (wr) yp[(size_t)t * Cc] = f2bf(yn / (den + 1e-6f));
  }
}

// ---------------- row LayerNorm -> fp32 out ----------------
__global__ __launch_bounds__(256) void k_ln(const float* __restrict__ pre, const float* __restrict__ ln_g,
    const float* __restrict__ ln_b, float* __restrict__ out) {
  int row = blockIdx.x;
  int tid = threadIdx.x;
  float4 v = *(const float4*)&pre[(size_t)row * Cc + tid * 4];
  float s = v.x + v.y + v.z + v.w;
  float q = v.x * v.x + v.y * v.y + v.z * v.z + v.w * v.w;
#pragma unroll
  for (int off = 1; off < 64; off <<= 1) {
    s += __shfl_xor(s, off);
    q += __shfl_xor(q, off);
  }
  __shared__ float ss[4], qq[4];
  if ((tid & 63) == 0) { ss[tid >> 6] = s; qq[tid >> 6] = q; }
  __syncthreads();
  s = ss[0] + ss[1] + ss[2] + ss[3];
  q = qq[0] + qq[1] + qq[2] + qq[3];
  float mu = s * (1.f / 1024.f);
  float var = q * (1.f / 1024.f) - mu * mu;
  float rstd = rsqrtf(var + 1e-5f);
  int c0 = tid * 4;
  float4 g = *(const float4*)&ln_g[c0];
  float4 bb = *(const float4*)&ln_b[c0];
  float4 o;
  o.x = (v.x - mu) * rstd * g.x + bb.x;
  o.y = (v.y - mu) * rstd * g.y + bb.y;
  o.z = (v.z - mu) * rstd * g.z + bb.z;
  o.w = (v.w - mu) * rstd * g.w + bb.w;
  *(float4*)&out[(size_t)row * Cc + c0] = o;
}

extern "C" void kernel_launch(void* const* d_in, const int* in_sizes, int n_in,
                              void* d_out, int out_size, void* d_ws, size_t ws_size,
                              hipStream_t stream) {
  const float* x        = (const float*)d_in[0];
  const float* q_w      = (const float*)d_in[1];
  const float* k_w      = (const float*)d_in[2];
  const float* v_w      = (const float*)d_in[3];
  const float* out_w    = (const float*)d_in[4];
  const float* out_b    = (const float*)d_in[5];
  const float* decay_w  = (const float*)d_in[6];
  const float* decay_b  = (const float*)d_in[7];
  const float* gate_w   = (const float*)d_in[8];
  const float* gate_b   = (const float*)d_in[9];
  const float* decay_w0 = (const float*)d_in[10];
  const float* ln_g     = (const float*)d_in[11];
  const float* ln_b     = (const float*)d_in[12];
  float* out            = (float*)d_out;

  const size_t MC  = (size_t)Mc * Cc;
  const size_t BHT = (size_t)Bc * Hc * Tc;
  const int NBH = Bc * Hc;                 // 32

  const bool fp32path = ws_size >= (size_t)52 * 1024 * 1024;

  if (fp32path) {
    char* p = (char*)d_ws;
    float* tabC = (float*)p;                    p += (size_t)Tc * 32 * 4;
    float* tabS = (float*)p;                    p += (size_t)Tc * 32 * 4;
    unsigned short* xbf   = (unsigned short*)p; p += MC * 2;        // S aliases (8 MiB)
    unsigned short* qwT   = (unsigned short*)p; p += (size_t)Cc * Cc * 2;
    unsigned short* kwT   = (unsigned short*)p; p += (size_t)Cc * Cc * 2;
    unsigned short* vwT   = (unsigned short*)p; p += (size_t)Cc * Cc * 2;
    unsigned short* owT   = (unsigned short*)p; p += (size_t)Cc * Cc * 2;
    unsigned short* phiQb = (unsigned short*)p; p += MC * 2;        // preO overlays phiQb+Vbf
    unsigned short* Vbf   = (unsigned short*)p; p += MC * 2;
    unsigned short* phiKb = (unsigned short*)p; p += MC * 2;
    unsigned short* Ybf   = (unsigned short*)p; p += MC * 2;
    float* rateB = (float*)p;                   p += BHT * 4;
    float* gateB = (float*)p;                   p += BHT * 4;
    float* Dsum  = (float*)p;                   p += (size_t)NBH * NCc * 64 * 4;
    float* Pbuf  = (float*)p;                   p += (size_t)NBH * NCc * 4;
    unsigned short* S = xbf;                    // xbf dead after projection GEMMs
    float* preO = (float*)phiQb;                // phiQb+Vbf dead after scanC2

    k_tables<<<(Tc * 32) / 256, 256, 0, stream>>>(tabC, tabS);
    k_trans<<<dim3(Cc / 32, Cc / 32, 4), 256, 0, stream>>>(q_w, k_w, v_w, out_w, qwT, kwT, vwT, owT);
    k_small<<<Mc, 256, 0, stream>>>(x, gate_w, gate_b, decay_w, decay_b, decay_w0, gateB, rateB, xbf);

    k_qkv<<<dim3(Cc / 128, Mc / 256, 3), 256, 0, stream>>>(xbf, qwT, kwT, vwT,
                                                           phiQb, phiKb, Vbf, tabC, tabS);

    k_scanA2<<<NBH * NCc, 256, 0, stream>>>(phiKb, Vbf, rateB, gateB, S, Dsum, Pbuf);
    k_scanB<<<NBH, 256, 0, stream>>>(S, Dsum, Pbuf);
    k_scanC2<<<NBH * NCc, 256, 0, stream>>>(phiQb, phiKb, Vbf, rateB, gateB, S, Dsum, Ybf);

    k_oproj<<<dim3(Cc / 128, Mc / 64), 256, 0, stream>>>(Ybf, owT, preO, out_b, x);
    k_ln<<<Mc, 256, 0, stream>>>(preO, ln_g, ln_b, out);
  } else {
    // ---- 33 MiB bf16-intermediate fallback (serial scan, SIMT GEMM) ----
    float* tabC  = (float*)d_ws;
    float* tabS  = tabC + (size_t)Tc * 32;
    unsigned short* phiQb = (unsigned short*)(tabS + (size_t)Tc * 32);
    unsigned short* phiKb = phiQb + MC;
    unsigned short* Vbb   = phiKb + MC;
    unsigned short* Ybb   = Vbb + MC;
    float* rateB = (float*)(Ybb + MC);
    float* gateB = rateB + BHT;
    float* preO  = (float*)phiQb;
    dim3 gg(Cc / 128, Mc / 128);

    k_tables<<<(Tc * 32) / 256, 256, 0, stream>>>(tabC, tabS);
    k_gemm128<float, unsigned short, 1><<<gg, 256, 0, stream>>>(x, q_w, phiQb, Mc, Cc, Cc, tabC, tabS, nullptr, nullptr);
    k_gemm128<float, unsigned short, 1><<<gg, 256, 0, stream>>>(x, k_w, phiKb, Mc, Cc, Cc, tabC, tabS, nullptr, nullptr);
    k_gemm128<float, unsigned short, 0><<<gg, 256, 0, stream>>>(x, v_w, Vbb, Mc, Cc, Cc, nullptr, nullptr, nullptr, nullptr);
    k_small<<<Mc, 256, 0, stream>>>(x, gate_w, gate_b, decay_w, decay_b, decay_w0, gateB, rateB, nullptr);
    k_scan<<<Bc * Hc, 256, 0, stream>>>(phiQb, phiKb, Vbb, rateB, gateB, Ybb);
    k_gemm128<unsigned short, float, 2><<<gg, 256, 0, stream>>>(Ybb, out_w, preO, Mc, Cc, Cc, nullptr, nullptr, out_b, x);
    k_ln<<<Mc, 256, 0, stream>>>(preO, ln_g, ln_b, out);
  }
}

// Round 12
// 142.438 us; speedup vs baseline: 1.1367x; 1.1367x over previous
//
#include <hip/hip_runtime.h>
#include <hip/hip_bf16.h>
#include <math.h>

static constexpr int Bc = 2, Tc = 2048, Cc = 1024, Hc = 16;
static constexpr int Mc = Bc * Tc;  // 4096 rows
static constexpr int NCc = 32, Lc = 64;  // chunks per (b,h), chunk length
static constexpr int TP = 72;  // LDS tile pitch (shorts) for scan kernels

typedef __attribute__((ext_vector_type(8))) short bf16x8;
typedef __attribute__((ext_vector_type(4))) float f32x4;

// ---------- dtype helpers ----------
__device__ __forceinline__ float bf2f(unsigned short u) {
  return __uint_as_float((unsigned)u << 16);
}
__device__ __forceinline__ unsigned short f2bf(float f) {
  __hip_bfloat16 h = __float2bfloat16(f);
  return *(unsigned short*)&h;
}
__device__ __forceinline__ float4 ld4(const float* p) { return *(const float4*)p; }
__device__ __forceinline__ float4 ld4(const unsigned short* p) {
  ushort4 u = *(const ushort4*)p;
  return make_float4(bf2f(u.x), bf2f(u.y), bf2f(u.z), bf2f(u.w));
}
__device__ __forceinline__ void stv(float* p, float v) { *p = v; }
__device__ __forceinline__ void stv(unsigned short* p, float v) { *p = f2bf(v); }

__device__ __forceinline__ void glds16(const unsigned short* src, unsigned short* dst) {
  __builtin_amdgcn_global_load_lds(
      (const __attribute__((address_space(1))) unsigned int*)src,
      (__attribute__((address_space(3))) unsigned int*)dst, 16, 0, 0);
}

// ---------------- RoPE tables ----------------
__global__ __launch_bounds__(256) void k_tables(float* __restrict__ tc, float* __restrict__ ts) {
  int i = blockIdx.x * 256 + threadIdx.x;       // < Tc*32
  int t = i >> 5, f = i & 31;
  float ivf = 1.0f / powf(10000.f, (float)f / 32.f);
  float fr = (float)t * ivf;
  tc[i] = cosf(fr);
  ts[i] = sinf(fr);
}

__device__ __forceinline__ float phi_fn(float x) { return x > 0.f ? x + 1.f : __expf(x); }

// ---------------- W[K][N] fp32 -> WT[N][K] bf16, 4 weights via blockIdx.z ----------------
__global__ __launch_bounds__(256) void k_trans(
    const float* __restrict__ w0, const float* __restrict__ w1,
    const float* __restrict__ w2, const float* __restrict__ w3,
    unsigned short* __restrict__ o0, unsigned short* __restrict__ o1,
    unsigned short* __restrict__ o2, unsigned short* __restrict__ o3) {
  const float* W = (blockIdx.z == 0) ? w0 : (blockIdx.z == 1) ? w1 : (blockIdx.z == 2) ? w2 : w3;
  unsigned short* O = (blockIdx.z == 0) ? o0 : (blockIdx.z == 1) ? o1 : (blockIdx.z == 2) ? o2 : o3;
  __shared__ float tile[32][33];
  int k0 = blockIdx.x * 32, n0 = blockIdx.y * 32;
  int t = threadIdx.x;
  int kk = t >> 3, nn4 = (t & 7) * 4;
  float4 v = *(const float4*)&W[(size_t)(k0 + kk) * Cc + n0 + nn4];
  tile[kk][nn4] = v.x; tile[kk][nn4 + 1] = v.y; tile[kk][nn4 + 2] = v.z; tile[kk][nn4 + 3] = v.w;
  __syncthreads();
  int nn = t >> 3, kk4 = (t & 7) * 4;
  ushort4 o = make_ushort4(f2bf(tile[kk4][nn]), f2bf(tile[kk4 + 1][nn]),
                           f2bf(tile[kk4 + 2][nn]), f2bf(tile[kk4 + 3][nn]));
  *(ushort4*)&O[(size_t)(n0 + nn) * Cc + k0 + kk4] = o;
}

// ================ pipelined MFMA GEMM core (counted-vmcnt, 3-buffer) ================
// ROUND-9 VERIFIED ORDERING: per-wave s_waitcnt vmcnt(NL) BEFORE s_barrier (each wave
// certifies its own stage(t) loads; barrier publishes to all waves), then issue
// stage(t+2). 2 stages stay in flight during compute; never drains mid-loop.
// Source-side XOR swizzle blk^=(row>>1)&3, matched on ds_read.
template <int FM, int FN>
__device__ __forceinline__ void stage_tiles(const unsigned short* __restrict__ A,
    const unsigned short* __restrict__ BT, unsigned short* As, unsigned short* Bs,
    int buf, int kt, int m0, int n0, int w, int l) {
  constexpr int BM = 32 * FM, BN = 32 * FN;
  const int srow = l >> 2, sblk = l & 3;
  const int k0 = kt * 32;
#pragma unroll
  for (int i = w; i < BM / 16; i += 4) {
    int row = i * 16 + srow;
    int blk = sblk ^ ((row >> 1) & 3);
    glds16(A + (size_t)(m0 + row) * Cc + k0 + blk * 8, As + buf * (BM * 32) + i * 512);
  }
#pragma unroll
  for (int i = w; i < BN / 16; i += 4) {
    int row = i * 16 + srow;
    int blk = sblk ^ ((row >> 1) & 3);
    glds16(BT + (size_t)(n0 + row) * Cc + k0 + blk * 8, Bs + buf * (BN * 32) + i * 512);
  }
}

template <int FM, int FN>
__device__ __forceinline__ void gemm_loop(const unsigned short* __restrict__ A,
    const unsigned short* __restrict__ BT,
    unsigned short* As, unsigned short* Bs, f32x4 (&acc)[FM][FN],
    int m0, int n0, int w, int l) {
  constexpr int BM = 32 * FM, BN = 32 * FN;
  constexpr int NT = Cc / 32;
  constexpr int NL = (BM + BN) / 64;   // glds16 per wave per stage
  const int wr = w >> 1, wc = w & 1;
  const int lrow = l & 15, lb = l >> 4;

  // prologue: tiles 0,1 into buffers 0,1
  stage_tiles<FM, FN>(A, BT, As, Bs, 0, 0, m0, n0, w, l);
  stage_tiles<FM, FN>(A, BT, As, Bs, 1, 1, m0, n0, w, l);

  int cur = 0, pre = 2;  // pre = (t+2)%3
  for (int t = 0; t < NT; ++t) {
    if (t + 1 < NT) {
      if constexpr (NL == 4) asm volatile("s_waitcnt vmcnt(4)" ::: "memory");
      else if constexpr (NL == 3) asm volatile("s_waitcnt vmcnt(3)" ::: "memory");
      else asm volatile("s_waitcnt vmcnt(0)" ::: "memory");
    } else {
      asm volatile("s_waitcnt vmcnt(0)" ::: "memory");
    }
    __builtin_amdgcn_s_barrier();
    if (t + 2 < NT) stage_tiles<FM, FN>(A, BT, As, Bs, pre, t + 2, m0, n0, w, l);

    const unsigned short* Ab = As + cur * (BM * 32);
    const unsigned short* Bb = Bs + cur * (BN * 32);
    bf16x8 af[FM], bf[FN];
#pragma unroll
    for (int fm = 0; fm < FM; ++fm) {
      int row = wr * 16 * FM + fm * 16 + lrow;
      af[fm] = *(const bf16x8*)&Ab[row * 32 + ((lb ^ ((row >> 1) & 3)) * 8)];
    }
#pragma unroll
    for (int fn = 0; fn < FN; ++fn) {
      int row = wc * 16 * FN + fn * 16 + lrow;
      bf[fn] = *(const bf16x8*)&Bb[row * 32 + ((lb ^ ((row >> 1) & 3)) * 8)];
    }
#pragma unroll
    for (int fm = 0; fm < FM; ++fm)
#pragma unroll
      for (int fn = 0; fn < FN; ++fn)
        acc[fm][fn] = __builtin_amdgcn_mfma_f32_16x16x32_bf16(af[fm], bf[fn], acc[fm][fn], 0, 0, 0);
    cur = (cur == 2) ? 0 : cur + 1;
    pre = (pre == 2) ? 0 : pre + 1;
  }
}

// ---------------- fused Q/K/V projections (blockIdx.z selects); 128x128 tile ----------------
__global__ __launch_bounds__(256) void k_qkv(const unsigned short* __restrict__ xbf,
    const unsigned short* __restrict__ qwT, const unsigned short* __restrict__ kwT,
    const unsigned short* __restrict__ vwT,
    unsigned short* __restrict__ Qo, unsigned short* __restrict__ Ko, unsigned short* __restrict__ Vo,
    const float* __restrict__ tabC, const float* __restrict__ tabS) {
  __shared__ unsigned short As[3 * 128 * 32];
  __shared__ unsigned short Bs[3 * 128 * 32];
  const int zz = blockIdx.z;
  const unsigned short* BT = (zz == 0) ? qwT : (zz == 1) ? kwT : vwT;
  unsigned short* Co = (zz == 0) ? Qo : (zz == 1) ? Ko : Vo;
  const int tid = threadIdx.x;
  const int l = tid & 63, w = tid >> 6;
  const int n0 = blockIdx.x * 128, m0 = blockIdx.y * 128;

  f32x4 acc[4][4];
#pragma unroll
  for (int i = 0; i < 4; ++i)
#pragma unroll
    for (int j = 0; j < 4; ++j) acc[i][j] = (f32x4){0.f, 0.f, 0.f, 0.f};

  gemm_loop<4, 4>(xbf, BT, As, Bs, acc, m0, n0, w, l);

  const int wr = w >> 1, wc = w & 1;
#pragma unroll
  for (int fm = 0; fm < 4; ++fm) {
#pragma unroll
    for (int fn = 0; fn < 4; ++fn) {
#pragma unroll
      for (int r = 0; r < 4; ++r) {
        float v = acc[fm][fn][r];
        int row = m0 + wr * 64 + fm * 16 + (l >> 4) * 4 + r;
        int col = n0 + wc * 64 + fn * 16 + (l & 15);
        if (zz < 2) {
          float p = __shfl_xor(v, 1);
          int t = row & (Tc - 1);
          int pi = (col & 63) >> 1;
          float cv = tabC[t * 32 + pi], sv = tabS[t * 32 + pi];
          float res = (col & 1) ? (p * sv + v * cv) : (v * cv - p * sv);
          Co[(size_t)row * Cc + col] = f2bf(phi_fn(res));
        } else {
          Co[(size_t)row * Cc + col] = f2bf(v);
        }
      }
    }
  }
}

// ---------------- out-proj: 64x128 tile, +bias +residual -> bf16 preO ----------------
__global__ __launch_bounds__(256) void k_oproj(const unsigned short* __restrict__ Ybf,
    const unsigned short* __restrict__ owT, unsigned short* __restrict__ Co,
    const float* __restrict__ bias, const float* __restrict__ resid) {
  __shared__ unsigned short As[3 * 64 * 32];
  __shared__ unsigned short Bs[3 * 128 * 32];
  const int tid = threadIdx.x;
  const int l = tid & 63, w = tid >> 6;
  const int n0 = blockIdx.x * 128, m0 = blockIdx.y * 64;

  f32x4 acc[2][4];
#pragma unroll
  for (int i = 0; i < 2; ++i)
#pragma unroll
    for (int j = 0; j < 4; ++j) acc[i][j] = (f32x4){0.f, 0.f, 0.f, 0.f};

  gemm_loop<2, 4>(Ybf, owT, As, Bs, acc, m0, n0, w, l);

  const int wr = w >> 1, wc = w & 1;
#pragma unroll
  for (int fm = 0; fm < 2; ++fm) {
#pragma unroll
    for (int fn = 0; fn < 4; ++fn) {
#pragma unroll
      for (int r = 0; r < 4; ++r) {
        int row = m0 + wr * 32 + fm * 16 + (l >> 4) * 4 + r;
        int col = n0 + wc * 64 + fn * 16 + (l & 15);
        Co[(size_t)row * Cc + col] = f2bf(acc[fm][fn][r] + bias[col] + resid[(size_t)row * Cc + col]);
      }
    }
  }
}

// ---------------- legacy fp32 SIMT GEMM (fallback path only) ----------------
template <typename AT, typename OT, int MODE>
__global__ __launch_bounds__(256) void k_gemm128(
    const AT* __restrict__ A, const float* __restrict__ Bw, OT* __restrict__ Co,
    int M, int N, int K,
    const float* __restrict__ tabC, const float* __restrict__ tabS,
    const float* __restrict__ bias, const float* __restrict__ resid) {
  __shared__ float As[16][132];
  __shared__ float Bs[16][132];
  const int tid = threadIdx.x;
  const int tx = tid & 15, ty = tid >> 4;
  const int n0 = blockIdx.x * 128, m0 = blockIdx.y * 128;
  float acc[8][8];
#pragma unroll
  for (int i = 0; i < 8; ++i)
#pragma unroll
    for (int j = 0; j < 8; ++j) acc[i][j] = 0.f;
  for (int k0 = 0; k0 < K; k0 += 16) {
#pragma unroll
    for (int rep = 0; rep < 2; ++rep) {
      int lin = tid + rep * 256;
      int r = lin >> 2, c4 = (lin & 3) << 2;
      float4 av = ld4(&A[(size_t)(m0 + r) * K + k0 + c4]);
      As[c4 + 0][r] = av.x; As[c4 + 1][r] = av.y;
      As[c4 + 2][r] = av.z; As[c4 + 3][r] = av.w;
      int rb = lin >> 5, cb = (lin & 31) << 2;
      *(float4*)&Bs[rb][cb] = *(const float4*)&Bw[(size_t)(k0 + rb) * N + n0 + cb];
    }
    __syncthreads();
#pragma unroll
    for (int kk = 0; kk < 16; ++kk) {
      float4 a0 = *(const float4*)&As[kk][ty * 8];
      float4 a1 = *(const float4*)&As[kk][ty * 8 + 4];
      float4 b0 = *(const float4*)&Bs[kk][tx * 8];
      float4 b1 = *(const float4*)&Bs[kk][tx * 8 + 4];
      float avv[8] = {a0.x, a0.y, a0.z, a0.w, a1.x, a1.y, a1.z, a1.w};
      float bvv[8] = {b0.x, b0.y, b0.z, b0.w, b1.x, b1.y, b1.z, b1.w};
#pragma unroll
      for (int i = 0; i < 8; ++i)
#pragma unroll
        for (int j = 0; j < 8; ++j) acc[i][j] = fmaf(avv[i], bvv[j], acc[i][j]);
    }
    __syncthreads();
  }
  if constexpr (MODE == 1) {
#pragma unroll
    for (int i = 0; i < 8; ++i) {
      int row = m0 + ty * 8 + i;
      int t = row & (Tc - 1);
#pragma unroll
      for (int j = 0; j < 8; j += 2) {
        int col = n0 + tx * 8 + j;
        int pi = (col & 63) >> 1;
        float cv = tabC[t * 32 + pi], sv = tabS[t * 32 + pi];
        float xe = acc[i][j], xo = acc[i][j + 1];
        stv(&Co[(size_t)row * N + col], phi_fn(xe * cv - xo * sv));
        stv(&Co[(size_t)row * N + col + 1], phi_fn(xe * sv + xo * cv));
      }
    }
  } else if constexpr (MODE == 2) {
#pragma unroll
    for (int i = 0; i < 8; ++i) {
      int row = m0 + ty * 8 + i;
#pragma unroll
      for (int j = 0; j < 8; ++j) {
        int col = n0 + tx * 8 + j;
        stv(&Co[(size_t)row * N + col], acc[i][j] + bias[col] + resid[(size_t)row * N + col]);
      }
    }
  } else {
#pragma unroll
    for (int i = 0; i < 8; ++i) {
      int row = m0 + ty * 8 + i;
#pragma unroll
      for (int j = 0; j < 8; ++j) {
        int col = n0 + tx * 8 + j;
        stv(&Co[(size_t)row * N + col], acc[i][j]);
      }
    }
  }
}

// ---------------- gate/decay projections (writes RATE) + fused x->bf16 ----------------
__global__ __launch_bounds__(256) void k_small(
    const float* __restrict__ x, const float* __restrict__ gate_w, const float* __restrict__ gate_b,
    const float* __restrict__ decay_w, const float* __restrict__ decay_b,
    const float* __restrict__ decay_w0, float* __restrict__ gate_o, float* __restrict__ rate_o,
    unsigned short* __restrict__ xbf_o) {
  __shared__ float xs[1024];
  __shared__ float part[8][32];
  int bt = blockIdx.x;
  int tid = threadIdx.x;
  float4 xv = *(const float4*)&x[(size_t)bt * Cc + tid * 4];
  *(float4*)&xs[tid * 4] = xv;
  if (xbf_o) {
    ushort4 u = make_ushort4(f2bf(xv.x), f2bf(xv.y), f2bf(xv.z), f2bf(xv.w));
    *(ushort4*)&xbf_o[(size_t)bt * Cc + tid * 4] = u;
  }
  __syncthreads();
  int o = tid & 31, seg = tid >> 5;
  const float* wp = (o < 16) ? gate_w : decay_w;
  int oc = o & 15;
  float p = 0.f;
  int kb = seg * 128;
#pragma unroll 4
  for (int kk = 0; kk < 128; ++kk) {
    int k = kb + kk;
    p = fmaf(xs[k], wp[(size_t)k * 16 + oc], p);
  }
  part[seg][o] = p;
  __syncthreads();
  if (tid < 32) {
    float s = 0.f;
#pragma unroll
    for (int sg = 0; sg < 8; ++sg) s += part[sg][tid];
    int b = bt >> 11, t = bt & (Tc - 1);
    if (tid < 16) {
      float gv = 1.f / (1.f + expf(-(s + gate_b[tid])));
      gate_o[((size_t)(b * Hc + tid)) * Tc + t] = gv;
    } else {
      int hh = tid - 16;
      float raw = s + decay_b[hh] + decay_w0[hh];
      float sp = raw > 20.f ? raw : log1pf(expf(raw));
      float rate = fminf(fmaxf(sp, 1e-4f), 10.f);
      rate_o[((size_t)(b * Hc + hh)) * Tc + t] = rate;
    }
  }
}

// ---------------- Phase A (MFMA): per-chunk summaries S^T[e][d], Dsum[d], P ----------------
__global__ __launch_bounds__(256) void k_scanA2(
    const unsigned short* __restrict__ Kb, const unsigned short* __restrict__ Vb,
    const float* __restrict__ rateB, const float* __restrict__ gateB,
    unsigned short* __restrict__ S, float* __restrict__ Dsum, float* __restrict__ Pbuf) {
  int blk = blockIdx.x;
  int bh = blk >> 5, c = blk & 31;
  int b = bh >> 4, h = bh & 15;
  int tid = threadIdx.x;
  int l = tid & 63, wv = tid >> 6;
  __shared__ unsigned short KT[64 * TP];   // [d][s]
  __shared__ unsigned short VT[64 * TP];   // [e][s], scaled by w_s
  __shared__ float Rc[64], gs[64], ws[64];
  size_t base = ((size_t)b * Tc + (size_t)c * 64) * Cc + h * 64;
  {
    int s = tid >> 2, d0g = (tid & 3) * 16;
    const unsigned short* kr = Kb + base + (size_t)s * Cc + d0g;
    unsigned short kv[16];
    *(uint4*)kv = *(const uint4*)kr; *(uint4*)(kv + 8) = *(const uint4*)(kr + 8);
#pragma unroll
    for (int i = 0; i < 16; ++i) KT[(d0g + i) * TP + s] = kv[i];
  }
  if (wv == 0) {
    float r = rateB[(size_t)bh * Tc + c * 64 + l];
    float g = gateB[(size_t)bh * Tc + c * 64 + l];
    float v = r;
#pragma unroll
    for (int off = 1; off < 64; off <<= 1) { float u = __shfl_up(v, off); if (l >= off) v += u; }
    Rc[l] = v; gs[l] = g;
  }
  __syncthreads();
  float Rtot = Rc[63];
  if (wv == 0) ws[l] = __expf(Rc[l] - Rtot) * gs[l];
  __syncthreads();
  {
    int s = tid >> 2, e0g = (tid & 3) * 16;
    float wsv = ws[s];
    const unsigned short* vr = Vb + base + (size_t)s * Cc + e0g;
    unsigned short vvv[16];
    *(uint4*)vvv = *(const uint4*)vr; *(uint4*)(vvv + 8) = *(const uint4*)(vr + 8);
#pragma unroll
    for (int i = 0; i < 16; ++i) VT[(e0g + i) * TP + s] = f2bf(bf2f(vvv[i]) * wsv);
  }
  __syncthreads();
  f32x4 acc[4];
#pragma unroll
  for (int i = 0; i < 4; ++i) acc[i] = (f32x4){0.f, 0.f, 0.f, 0.f};
  const int lrow = l & 15, lk8 = (l >> 4) * 8;
#pragma unroll
  for (int ks = 0; ks < 2; ++ks) {
    bf16x8 a = *(const bf16x8*)&VT[(wv * 16 + lrow) * TP + ks * 32 + lk8];
#pragma unroll
    for (int fn = 0; fn < 4; ++fn) {
      bf16x8 bb = *(const bf16x8*)&KT[(fn * 16 + lrow) * TP + ks * 32 + lk8];
      acc[fn] = __builtin_amdgcn_mfma_f32_16x16x32_bf16(a, bb, acc[fn], 0, 0, 0);
    }
  }
  size_t sb = (size_t)blk * 4096;
#pragma unroll
  for (int fn = 0; fn < 4; ++fn)
#pragma unroll
    for (int r = 0; r < 4; ++r) {
      int e = wv * 16 + (l >> 4) * 4 + r;
      int d = fn * 16 + (l & 15);
      S[sb + e * 64 + d] = f2bf(acc[fn][r]);
    }
  if (tid < 64) {
    float s = 0.f;
#pragma unroll 8
    for (int ss = 0; ss < 64; ++ss) s += bf2f(KT[tid * TP + ss]) * ws[ss];
    Dsum[(size_t)blk * 64 + tid] = s;
  }
  if (tid == 0) Pbuf[blk] = __expf(-Rtot);
}

// ---------------- Phase B: serial carry across chunks (1-deep prefetch) ----------------
__global__ __launch_bounds__(256) void k_scanB(unsigned short* __restrict__ S, float* __restrict__ Dsum,
                                               const float* __restrict__ Pbuf) {
  int bh = blockIdx.x;
  int tid = threadIdx.x;
  float Nreg[16];
#pragma unroll
  for (int k = 0; k < 16; ++k) Nreg[k] = 0.f;
  float Dreg = 0.f;
  unsigned short curS[16]; float curD = 0.f, curP;
  {
    size_t sb = ((size_t)bh * NCc) * 4096;
#pragma unroll
    for (int k = 0; k < 16; ++k) curS[k] = S[sb + tid + k * 256];
    if (tid < 64) curD = Dsum[((size_t)bh * NCc) * 64 + tid];
    curP = Pbuf[bh * NCc];
  }
  for (int c = 0; c < NCc; ++c) {
    unsigned short nxtS[16]; float nxtD = 0.f, nxtP = 0.f;
    if (c + 1 < NCc) {
      size_t sb = ((size_t)bh * NCc + c + 1) * 4096;
#pragma unroll
      for (int k = 0; k < 16; ++k) nxtS[k] = S[sb + tid + k * 256];
      if (tid < 64) nxtD = Dsum[((size_t)bh * NCc + c + 1) * 64 + tid];
      nxtP = Pbuf[bh * NCc + c + 1];
    }
    size_t sb = ((size_t)bh * NCc + c) * 4096;
#pragma unroll
    for (int k = 0; k < 16; ++k) {
      float tmp = bf2f(curS[k]);
      S[sb + tid + k * 256] = f2bf(Nreg[k]);
      Nreg[k] = Nreg[k] * curP + tmp;
    }
    if (tid < 64) {
      size_t db = ((size_t)bh * NCc + c) * 64 + tid;
      float tmp = curD;
      Dsum[db] = Dreg;
      Dreg = Dreg * curP + tmp;
    }
#pragma unroll
    for (int k = 0; k < 16; ++k) curS[k] = nxtS[k];
    curD = nxtD; curP = nxtP;
  }
}

// ---------------- Phase C (MFMA): intra-chunk + start-state, full output ----------------
__global__ __launch_bounds__(256) void k_scanC2(
    const unsigned short* __restrict__ Qb, const unsigned short* __restrict__ Kb,
    const unsigned short* __restrict__ Vb,
    const float* __restrict__ rateB, const float* __restrict__ gateB,
    const unsigned short* __restrict__ S, const float* __restrict__ Dsum,
    unsigned short* __restrict__ Yb) {
  int blk = blockIdx.x;
  int bh = blk >> 5, c = blk & 31;
  int b = bh >> 4, h = bh & 15;
  int tid = threadIdx.x;
  int l = tid & 63, wv = tid >> 6;
  __shared__ unsigned short Qs[64 * TP];
  __shared__ unsigned short Ks[64 * TP];   // overlaid by W' after QK
  __shared__ unsigned short VT[64 * TP];
  __shared__ unsigned short Ss[64 * TP];
  __shared__ float Rc[64], gs[64], DstL[64];
  size_t base = ((size_t)b * Tc + (size_t)c * 64) * Cc + h * 64;
  {
    int rr = tid >> 2, c0 = (tid & 3) * 16;
    const unsigned short* qr = Qb + base + (size_t)rr * Cc + c0;
    const unsigned short* kr = Kb + base + (size_t)rr * Cc + c0;
    const unsigned short* vr = Vb + base + (size_t)rr * Cc + c0;
    const unsigned short* sr = S + (size_t)blk * 4096 + rr * 64 + c0;
    *(uint4*)&Qs[rr * TP + c0] = *(const uint4*)qr;
    *(uint4*)&Qs[rr * TP + c0 + 8] = *(const uint4*)(qr + 8);
    *(uint4*)&Ks[rr * TP + c0] = *(const uint4*)kr;
    *(uint4*)&Ks[rr * TP + c0 + 8] = *(const uint4*)(kr + 8);
    *(uint4*)&Ss[rr * TP + c0] = *(const uint4*)sr;
    *(uint4*)&Ss[rr * TP + c0 + 8] = *(const uint4*)(sr + 8);
    unsigned short vvv[16];
    *(uint4*)vvv = *(const uint4*)vr; *(uint4*)(vvv + 8) = *(const uint4*)(vr + 8);
#pragma unroll
    for (int i = 0; i < 16; ++i) VT[(c0 + i) * TP + rr] = vvv[i];
  }
  if (wv == 0) {
    float r = rateB[(size_t)bh * Tc + c * 64 + l];
    float g = gateB[(size_t)bh * Tc + c * 64 + l];
    float v = r;
#pragma unroll
    for (int off = 1; off < 64; off <<= 1) { float u = __shfl_up(v, off); if (l >= off) v += u; }
    Rc[l] = v; gs[l] = g;
    DstL[l] = Dsum[(size_t)blk * 64 + l];
  }
  __syncthreads();
  const int lrow = l & 15, lk8 = (l >> 4) * 8;
  f32x4 qk[4];
#pragma unroll
  for (int i = 0; i < 4; ++i) qk[i] = (f32x4){0.f, 0.f, 0.f, 0.f};
#pragma unroll
  for (int ks = 0; ks < 2; ++ks) {
    bf16x8 a = *(const bf16x8*)&Qs[(wv * 16 + lrow) * TP + ks * 32 + lk8];
#pragma unroll
    for (int fn = 0; fn < 4; ++fn) {
      bf16x8 bb = *(const bf16x8*)&Ks[(fn * 16 + lrow) * TP + ks * 32 + lk8];
      qk[fn] = __builtin_amdgcn_mfma_f32_16x16x32_bf16(a, bb, qk[fn], 0, 0, 0);
    }
  }
  __syncthreads();
  float deni[4] = {0.f, 0.f, 0.f, 0.f};
  float rct[4];
#pragma unroll
  for (int r = 0; r < 4; ++r) rct[r] = Rc[wv * 16 + (l >> 4) * 4 + r];
#pragma unroll
  for (int fn = 0; fn < 4; ++fn) {
    int s = fn * 16 + (l & 15);
    float rs = Rc[s], g = gs[s];
#pragma unroll
    for (int r = 0; r < 4; ++r) {
      int t = wv * 16 + (l >> 4) * 4 + r;
      float wgt = (s <= t) ? __expf(rs - rct[r]) * g : 0.f;
      unsigned short sb16 = f2bf(qk[fn][r] * wgt);
      deni[r] += bf2f(sb16);
      Ks[t * TP + s] = sb16;
    }
  }
#pragma unroll
  for (int r = 0; r < 4; ++r) {
    deni[r] += __shfl_xor(deni[r], 1);
    deni[r] += __shfl_xor(deni[r], 2);
    deni[r] += __shfl_xor(deni[r], 4);
    deni[r] += __shfl_xor(deni[r], 8);
  }
  f32x4 nm[4], nm2[4], dn2;
#pragma unroll
  for (int i = 0; i < 4; ++i) { nm[i] = (f32x4){0.f,0.f,0.f,0.f}; nm2[i] = (f32x4){0.f,0.f,0.f,0.f}; }
  dn2 = (f32x4){0.f, 0.f, 0.f, 0.f};
#pragma unroll
  for (int ks = 0; ks < 2; ++ks) {
    bf16x8 aw = *(const bf16x8*)&Ks[(wv * 16 + lrow) * TP + ks * 32 + lk8];
    bf16x8 aq = *(const bf16x8*)&Qs[(wv * 16 + lrow) * TP + ks * 32 + lk8];
#pragma unroll
    for (int fn = 0; fn < 4; ++fn) {
      bf16x8 bv = *(const bf16x8*)&VT[(fn * 16 + lrow) * TP + ks * 32 + lk8];
      bf16x8 bs = *(const bf16x8*)&Ss[(fn * 16 + lrow) * TP + ks * 32 + lk8];
      nm[fn] = __builtin_amdgcn_mfma_f32_16x16x32_bf16(aw, bv, nm[fn], 0, 0, 0);
      nm2[fn] = __builtin_amdgcn_mfma_f32_16x16x32_bf16(aq, bs, nm2[fn], 0, 0, 0);
    }
    bf16x8 bd = (bf16x8){0, 0, 0, 0, 0, 0, 0, 0};
    if (lrow == 0) {
#pragma unroll
      for (int i = 0; i < 8; ++i) bd[i] = (short)f2bf(DstL[ks * 32 + lk8 + i]);
    }
    dn2 = __builtin_amdgcn_mfma_f32_16x16x32_bf16(aq, bd, dn2, 0, 0, 0);
  }
  float den2v[4];
#pragma unroll
  for (int r = 0; r < 4; ++r) den2v[r] = __shfl(dn2[r], (l & 48));
#pragma unroll
  for (int r = 0; r < 4; ++r) {
    int t = wv * 16 + (l >> 4) * 4 + r;
    float at = __expf(-rct[r]);
    float dv = deni[r] + at * den2v[r] + 1e-6f;
#pragma unroll
    for (int fn = 0; fn < 4; ++fn) {
      int e = fn * 16 + (l & 15);
      float numv = nm[fn][r] + at * nm2[fn][r];
      Yb[base + (size_t)t * Cc + e] = f2bf(numv / dv);
    }
  }
}

// ---------------- legacy serial scan (fallback path only; rate input) ----------------
__device__ __forceinline__ void load16(const unsigned short* __restrict__ p, float* d) {
  uint4 u = *(const uint4*)p;
  uint4 v = *(const uint4*)(p + 8);
  d[0] = __uint_as_float(u.x << 16); d[1] = __uint_as_float(u.x & 0xFFFF0000u);
  d[2] = __uint_as_float(u.y << 16); d[3] = __uint_as_float(u.y & 0xFFFF0000u);
  d[4] = __uint_as_float(u.z << 16); d[5] = __uint_as_float(u.z & 0xFFFF0000u);
  d[6] = __uint_as_float(u.w << 16); d[7] = __uint_as_float(u.w & 0xFFFF0000u);
  d[8] = __uint_as_float(v.x << 16); d[9] = __uint_as_float(v.x & 0xFFFF0000u);
  d[10] = __uint_as_float(v.y << 16); d[11] = __uint_as_float(v.y & 0xFFFF0000u);
  d[12] = __uint_as_float(v.z << 16); d[13] = __uint_as_float(v.z & 0xFFFF0000u);
  d[14] = __uint_as_float(v.w << 16); d[15] = __uint_as_float(v.w & 0xFFFF0000u);
}

__global__ __launch_bounds__(256) void k_scan(const unsigned short* __restrict__ phiQ,
    const unsigned short* __restrict__ phiK, const unsigned short* __restrict__ Vb,
    const float* __restrict__ rateB, const float* __restrict__ gateB,
    unsigned short* __restrict__ Yb) {
  int bh = blockIdx.x;
  int b = bh >> 4, h = bh & 15;
  int tid = threadIdx.x;
  int w = tid >> 6, l = tid & 63;
  int e = (w << 4) | (l & 15);
  int d0 = (l >> 4) << 4;
  size_t base = ((size_t)b * Tc) * Cc + h * 64;
  const unsigned short* qp = phiQ + base + d0;
  const unsigned short* kp = phiK + base + d0;
  const unsigned short* vp = Vb + base + e;
  const float* bp = rateB + (size_t)bh * Tc;
  const float* gp = gateB + (size_t)bh * Tc;
  unsigned short* yp = Yb + base + e;
  float Ns[16], Ds[16];
#pragma unroll
  for (int j = 0; j < 16; ++j) { Ns[j] = 0.f; Ds[j] = 0.f; }
  const bool wr = (l < 16);
  for (int t = 0; t < Tc; ++t) {
    float q[16], k[16];
    load16(qp + (size_t)t * Cc, q);
    load16(kp + (size_t)t * Cc, k);
    float vv = bf2f(vp[(size_t)t * Cc]);
    float btv = __expf(-bp[t]), gtv = gp[t];
    float yn = 0.f, den = 0.f;
#pragma unroll
    for (int j = 0; j < 16; ++j) {
      float wj = k[j] * gtv;
      float ns = fmaf(Ns[j], btv, wj * vv);
      float ds = fmaf(Ds[j], btv, wj);
      Ns[j] = ns; Ds[j] = ds;
      yn = fmaf(q[j], ns, yn);
      den = fmaf(q[j], ds, den);
    }
    yn += __shfl_xor(yn, 16); yn += __shfl_xor(yn, 32);
    den += __shfl_xor(den, 16); den += __shfl_xor(den, 32);
    if (wr) yp[(size_t)t * Cc] = f2bf(yn / (den + 1e-6f));
  }
}

// ---------------- row LayerNorm -> fp32 out (templated input) ----------------
template <typename PT>
__global__ __launch_bounds__(256) void k_ln(const PT* __restrict__ pre, const float* __restrict__ ln_g,
    const float* __restrict__ ln_b, float* __restrict__ out) {
  int row = blockIdx.x;
  int tid = threadIdx.x;
  float4 v = ld4(&pre[(size_t)row * Cc + tid * 4]);
  float s = v.x + v.y + v.z + v.w;
  float q = v.x * v.x + v.y * v.y + v.z * v.z + v.w * v.w;
#pragma unroll
  for (int off = 1; off < 64; off <<= 1) {
    s += __shfl_xor(s, off);
    q += __shfl_xor(q, off);
  }
  __shared__ float ss[4], qq[4];
  if ((tid & 63) == 0) { ss[tid >> 6] = s; qq[tid >> 6] = q; }
  __syncthreads();
  s = ss[0] + ss[1] + ss[2] + ss[3];
  q = qq[0] + qq[1] + qq[2] + qq[3];
  float mu = s * (1.f / 1024.f);
  float var = q * (1.f / 1024.f) - mu * mu;
  float rstd = rsqrtf(var + 1e-5f);
  int c0 = tid * 4;
  float4 g = *(const float4*)&ln_g[c0];
  float4 bb = *(const float4*)&ln_b[c0];
  float4 o;
  o.x = (v.x - mu) * rstd * g.x + bb.x;
  o.y = (v.y - mu) * rstd * g.y + bb.y;
  o.z = (v.z - mu) * rstd * g.z + bb.z;
  o.w = (v.w - mu) * rstd * g.w + bb.w;
  *(float4*)&out[(size_t)row * Cc + c0] = o;
}

extern "C" void kernel_launch(void* const* d_in, const int* in_sizes, int n_in,
                              void* d_out, int out_size, void* d_ws, size_t ws_size,
                              hipStream_t stream) {
  const float* x        = (const float*)d_in[0];
  const float* q_w      = (const float*)d_in[1];
  const float* k_w      = (const float*)d_in[2];
  const float* v_w      = (const float*)d_in[3];
  const float* out_w    = (const float*)d_in[4];
  const float* out_b    = (const float*)d_in[5];
  const float* decay_w  = (const float*)d_in[6];
  const float* decay_b  = (const float*)d_in[7];
  const float* gate_w   = (const float*)d_in[8];
  const float* gate_b   = (const float*)d_in[9];
  const float* decay_w0 = (const float*)d_in[10];
  const float* ln_g     = (const float*)d_in[11];
  const float* ln_b     = (const float*)d_in[12];
  float* out            = (float*)d_out;

  const size_t MC  = (size_t)Mc * Cc;
  const size_t BHT = (size_t)Bc * Hc * Tc;
  const int NBH = Bc * Hc;                 // 32

  const bool fp32path = ws_size >= (size_t)52 * 1024 * 1024;

  if (fp32path) {
    char* p = (char*)d_ws;
    float* tabC = (float*)p;                    p += (size_t)Tc * 32 * 4;
    float* tabS = (float*)p;                    p += (size_t)Tc * 32 * 4;
    unsigned short* xbf   = (unsigned short*)p; p += MC * 2;        // S aliases (8 MiB)
    unsigned short* qwT   = (unsigned short*)p; p += (size_t)Cc * Cc * 2;
    unsigned short* kwT   = (unsigned short*)p; p += (size_t)Cc * Cc * 2;
    unsigned short* vwT   = (unsigned short*)p; p += (size_t)Cc * Cc * 2;
    unsigned short* owT   = (unsigned short*)p; p += (size_t)Cc * Cc * 2;
    unsigned short* phiQb = (unsigned short*)p; p += MC * 2;        // preO (bf16) overlays phiQb
    unsigned short* Vbf   = (unsigned short*)p; p += MC * 2;
    unsigned short* phiKb = (unsigned short*)p; p += MC * 2;
    unsigned short* Ybf   = (unsigned short*)p; p += MC * 2;
    float* rateB = (float*)p;                   p += BHT * 4;
    float* gateB = (float*)p;                   p += BHT * 4;
    float* Dsum  = (float*)p;                   p += (size_t)NBH * NCc * 64 * 4;
    float* Pbuf  = (float*)p;                   p += (size_t)NBH * NCc * 4;
    unsigned short* S = xbf;                    // xbf dead after projection GEMMs
    unsigned short* preO = phiQb;               // phiQb dead after scanC2

    k_tables<<<(Tc * 32) / 256, 256, 0, stream>>>(tabC, tabS);
    k_trans<<<dim3(Cc / 32, Cc / 32, 4), 256, 0, stream>>>(q_w, k_w, v_w, out_w, qwT, kwT, vwT, owT);
    k_small<<<Mc, 256, 0, stream>>>(x, gate_w, gate_b, decay_w, decay_b, decay_w0, gateB, rateB, xbf);

    k_qkv<<<dim3(Cc / 128, Mc / 128, 3), 256, 0, stream>>>(xbf, qwT, kwT, vwT,
                                                           phiQb, phiKb, Vbf, tabC, tabS);

    k_scanA2<<<NBH * NCc, 256, 0, stream>>>(phiKb, Vbf, rateB, gateB, S, Dsum, Pbuf);
    k_scanB<<<NBH, 256, 0, stream>>>(S, Dsum, Pbuf);
    k_scanC2<<<NBH * NCc, 256, 0, stream>>>(phiQb, phiKb, Vbf, rateB, gateB, S, Dsum, Ybf);

    k_oproj<<<dim3(Cc / 128, Mc / 64), 256, 0, stream>>>(Ybf, owT, preO, out_b, x);
    k_ln<unsigned short><<<Mc, 256, 0, stream>>>(preO, ln_g, ln_b, out);
  } else {
    // ---- 33 MiB bf16-intermediate fallback (serial scan, SIMT GEMM) ----
    float* tabC  = (float*)d_ws;
    float* tabS  = tabC + (size_t)Tc * 32;
    unsigned short* phiQb = (unsigned short*)(tabS + (size_t)Tc * 32);
    unsigned short* phiKb = phiQb + MC;
    unsigned short* Vbb   = phiKb + MC;
    unsigned short* Ybb   = Vbb + MC;
    float* rateB = (float*)(Ybb + MC);
    float* gateB = rateB + BHT;
    float* preO  = (float*)phiQb;
    dim3 gg(Cc / 128, Mc / 128);

    k_tables<<<(Tc * 32) / 256, 256, 0, stream>>>(tabC, tabS);
    k_gemm128<float, unsigned short, 1><<<gg, 256, 0, stream>>>(x, q_w, phiQb, Mc, Cc, Cc, tabC, tabS, nullptr, nullptr);
    k_gemm128<float, unsigned short, 1><<<gg, 256, 0, stream>>>(x, k_w, phiKb, Mc, Cc, Cc, tabC, tabS, nullptr, nullptr);
    k_gemm128<float, unsigned short, 0><<<gg, 256, 0, stream>>>(x, v_w, Vbb, Mc, Cc, Cc, nullptr, nullptr, nullptr, nullptr);
    k_small<<<Mc, 256, 0, stream>>>(x, gate_w, gate_b, decay_w, decay_b, decay_w0, gateB, rateB, nullptr);
    k_scan<<<Bc * Hc, 256, 0, stream>>>(phiQb, phiKb, Vbb, rateB, gateB, Ybb);
    k_gemm128<unsigned short, float, 2><<<gg, 256, 0, stream>>>(Ybb, out_w, preO, Mc, Cc, Cc, nullptr, nullptr, out_b, x);
    k_ln<float><<<Mc, 256, 0, stream>>>(preO, ln_g, ln_b, out);
  }
}

// Round 13
// 131.670 us; speedup vs baseline: 1.2296x; 1.0818x over previous
//
#include <hip/hip_runtime.h>
#include <hip/hip_bf16.h>
#include <math.h>

static constexpr int Bc = 2, Tc = 2048, Cc = 1024, Hc = 16;
static constexpr int Mc = Bc * Tc;  // 4096 rows
static constexpr int NCc = 32, Lc = 64;  // chunks per (b,h), chunk length
static constexpr int TP = 72;  // LDS tile pitch (shorts) for scan kernels
static constexpr int SBP = 8;  // scanB element-partitions per bh

typedef __attribute__((ext_vector_type(8))) short bf16x8;
typedef __attribute__((ext_vector_type(4))) float f32x4;

// ---------- dtype helpers ----------
__device__ __forceinline__ float bf2f(unsigned short u) {
  return __uint_as_float((unsigned)u << 16);
}
__device__ __forceinline__ unsigned short f2bf(float f) {
  __hip_bfloat16 h = __float2bfloat16(f);
  return *(unsigned short*)&h;
}
__device__ __forceinline__ float4 ld4(const float* p) { return *(const float4*)p; }
__device__ __forceinline__ float4 ld4(const unsigned short* p) {
  ushort4 u = *(const ushort4*)p;
  return make_float4(bf2f(u.x), bf2f(u.y), bf2f(u.z), bf2f(u.w));
}
__device__ __forceinline__ void stv(float* p, float v) { *p = v; }
__device__ __forceinline__ void stv(unsigned short* p, float v) { *p = f2bf(v); }

__device__ __forceinline__ void glds16(const unsigned short* src, unsigned short* dst) {
  __builtin_amdgcn_global_load_lds(
      (const __attribute__((address_space(1))) unsigned int*)src,
      (__attribute__((address_space(3))) unsigned int*)dst, 16, 0, 0);
}

__device__ __forceinline__ float phi_fn(float x) { return x > 0.f ? x + 1.f : __expf(x); }

// ---------------- merged preprocessing: gate/decay proj + x->bf16 | weight transpose | RoPE tables ----------------
// grid: [0,4096) k_small rows; [4096,8192) weight-transpose tiles; [8192,8448) RoPE table
__global__ __launch_bounds__(256) void k_pre(
    const float* __restrict__ x, const float* __restrict__ gate_w, const float* __restrict__ gate_b,
    const float* __restrict__ decay_w, const float* __restrict__ decay_b,
    const float* __restrict__ decay_w0, float* __restrict__ gate_o, float* __restrict__ rate_o,
    unsigned short* __restrict__ xbf_o,
    const float* __restrict__ w0, const float* __restrict__ w1,
    const float* __restrict__ w2, const float* __restrict__ w3,
    unsigned short* __restrict__ o0, unsigned short* __restrict__ o1,
    unsigned short* __restrict__ o2, unsigned short* __restrict__ o3,
    float* __restrict__ tabC, float* __restrict__ tabS) {
  __shared__ float xs[1024];
  __shared__ float part[8][32];
  __shared__ float tile[32][33];
  const int bid = blockIdx.x;
  const int tid = threadIdx.x;
  if (bid < Mc) {
    // ---- gate/decay projections + x->bf16 ----
    int bt = bid;
    float4 xv = *(const float4*)&x[(size_t)bt * Cc + tid * 4];
    *(float4*)&xs[tid * 4] = xv;
    ushort4 u = make_ushort4(f2bf(xv.x), f2bf(xv.y), f2bf(xv.z), f2bf(xv.w));
    *(ushort4*)&xbf_o[(size_t)bt * Cc + tid * 4] = u;
    __syncthreads();
    int o = tid & 31, seg = tid >> 5;
    const float* wp = (o < 16) ? gate_w : decay_w;
    int oc = o & 15;
    float p = 0.f;
    int kb = seg * 128;
#pragma unroll 4
    for (int kk = 0; kk < 128; ++kk) {
      int k = kb + kk;
      p = fmaf(xs[k], wp[(size_t)k * 16 + oc], p);
    }
    part[seg][o] = p;
    __syncthreads();
    if (tid < 32) {
      float s = 0.f;
#pragma unroll
      for (int sg = 0; sg < 8; ++sg) s += part[sg][tid];
      int b = bt >> 11, t = bt & (Tc - 1);
      if (tid < 16) {
        float gv = 1.f / (1.f + expf(-(s + gate_b[tid])));
        gate_o[((size_t)(b * Hc + tid)) * Tc + t] = gv;
      } else {
        int hh = tid - 16;
        float raw = s + decay_b[hh] + decay_w0[hh];
        float sp = raw > 20.f ? raw : log1pf(expf(raw));
        float rate = fminf(fmaxf(sp, 1e-4f), 10.f);
        rate_o[((size_t)(b * Hc + hh)) * Tc + t] = rate;
      }
    }
  } else if (bid < 2 * Mc) {
    // ---- W[K][N] fp32 -> WT[N][K] bf16 ----
    int id = bid - Mc;
    int z = id >> 10, rem = id & 1023;
    int k0 = (rem & 31) * 32, n0 = (rem >> 5) * 32;
    const float* W = (z == 0) ? w0 : (z == 1) ? w1 : (z == 2) ? w2 : w3;
    unsigned short* O = (z == 0) ? o0 : (z == 1) ? o1 : (z == 2) ? o2 : o3;
    int kk = tid >> 3, nn4 = (tid & 7) * 4;
    float4 v = *(const float4*)&W[(size_t)(k0 + kk) * Cc + n0 + nn4];
    tile[kk][nn4] = v.x; tile[kk][nn4 + 1] = v.y; tile[kk][nn4 + 2] = v.z; tile[kk][nn4 + 3] = v.w;
    __syncthreads();
    int nn = tid >> 3, kk4 = (tid & 7) * 4;
    ushort4 o = make_ushort4(f2bf(tile[kk4][nn]), f2bf(tile[kk4 + 1][nn]),
                             f2bf(tile[kk4 + 2][nn]), f2bf(tile[kk4 + 3][nn]));
    *(ushort4*)&O[(size_t)(n0 + nn) * Cc + k0 + kk4] = o;
  } else {
    // ---- RoPE tables ----
    int i = (bid - 2 * Mc) * 256 + tid;   // < Tc*32
    int t = i >> 5, f = i & 31;
    float ivf = 1.0f / powf(10000.f, (float)f / 32.f);
    float fr = (float)t * ivf;
    tabC[i] = cosf(fr);
    tabS[i] = sinf(fr);
  }
}

// ================ pipelined MFMA GEMM core (counted-vmcnt, 3-buffer) ================
// Per-wave s_waitcnt vmcnt(NL) BEFORE s_barrier (each wave certifies its own stage(t)
// loads; barrier publishes to all waves), then issue stage(t+2). Never drains mid-loop.
// Source-side XOR swizzle blk^=(row>>1)&3, matched on ds_read. s_setprio around MFMA (T5).
template <int FM, int FN>
__device__ __forceinline__ void stage_tiles(const unsigned short* __restrict__ A,
    const unsigned short* __restrict__ BT, unsigned short* As, unsigned short* Bs,
    int buf, int kt, int m0, int n0, int w, int l) {
  constexpr int BM = 32 * FM, BN = 32 * FN;
  const int srow = l >> 2, sblk = l & 3;
  const int k0 = kt * 32;
#pragma unroll
  for (int i = w; i < BM / 16; i += 4) {
    int row = i * 16 + srow;
    int blk = sblk ^ ((row >> 1) & 3);
    glds16(A + (size_t)(m0 + row) * Cc + k0 + blk * 8, As + buf * (BM * 32) + i * 512);
  }
#pragma unroll
  for (int i = w; i < BN / 16; i += 4) {
    int row = i * 16 + srow;
    int blk = sblk ^ ((row >> 1) & 3);
    glds16(BT + (size_t)(n0 + row) * Cc + k0 + blk * 8, Bs + buf * (BN * 32) + i * 512);
  }
}

template <int FM, int FN>
__device__ __forceinline__ void gemm_loop(const unsigned short* __restrict__ A,
    const unsigned short* __restrict__ BT,
    unsigned short* As, unsigned short* Bs, f32x4 (&acc)[FM][FN],
    int m0, int n0, int w, int l) {
  constexpr int BM = 32 * FM, BN = 32 * FN;
  constexpr int NT = Cc / 32;
  constexpr int NL = (BM + BN) / 64;   // glds16 per wave per stage
  const int wr = w >> 1, wc = w & 1;
  const int lrow = l & 15, lb = l >> 4;

  stage_tiles<FM, FN>(A, BT, As, Bs, 0, 0, m0, n0, w, l);
  stage_tiles<FM, FN>(A, BT, As, Bs, 1, 1, m0, n0, w, l);

  int cur = 0, pre = 2;  // pre = (t+2)%3
  for (int t = 0; t < NT; ++t) {
    if (t + 1 < NT) {
      if constexpr (NL == 4) asm volatile("s_waitcnt vmcnt(4)" ::: "memory");
      else if constexpr (NL == 3) asm volatile("s_waitcnt vmcnt(3)" ::: "memory");
      else asm volatile("s_waitcnt vmcnt(0)" ::: "memory");
    } else {
      asm volatile("s_waitcnt vmcnt(0)" ::: "memory");
    }
    __builtin_amdgcn_s_barrier();
    if (t + 2 < NT) stage_tiles<FM, FN>(A, BT, As, Bs, pre, t + 2, m0, n0, w, l);

    const unsigned short* Ab = As + cur * (BM * 32);
    const unsigned short* Bb = Bs + cur * (BN * 32);
    bf16x8 af[FM], bf[FN];
#pragma unroll
    for (int fm = 0; fm < FM; ++fm) {
      int row = wr * 16 * FM + fm * 16 + lrow;
      af[fm] = *(const bf16x8*)&Ab[row * 32 + ((lb ^ ((row >> 1) & 3)) * 8)];
    }
#pragma unroll
    for (int fn = 0; fn < FN; ++fn) {
      int row = wc * 16 * FN + fn * 16 + lrow;
      bf[fn] = *(const bf16x8*)&Bb[row * 32 + ((lb ^ ((row >> 1) & 3)) * 8)];
    }
    __builtin_amdgcn_s_setprio(1);
#pragma unroll
    for (int fm = 0; fm < FM; ++fm)
#pragma unroll
      for (int fn = 0; fn < FN; ++fn)
        acc[fm][fn] = __builtin_amdgcn_mfma_f32_16x16x32_bf16(af[fm], bf[fn], acc[fm][fn], 0, 0, 0);
    __builtin_amdgcn_s_setprio(0);
    cur = (cur == 2) ? 0 : cur + 1;
    pre = (pre == 2) ? 0 : pre + 1;
  }
}

// ---------------- fused Q/K/V projections (blockIdx.z selects); 128x128 tile ----------------
__global__ __launch_bounds__(256) void k_qkv(const unsigned short* __restrict__ xbf,
    const unsigned short* __restrict__ qwT, const unsigned short* __restrict__ kwT,
    const unsigned short* __restrict__ vwT,
    unsigned short* __restrict__ Qo, unsigned short* __restrict__ Ko, unsigned short* __restrict__ Vo,
    const float* __restrict__ tabC, const float* __restrict__ tabS) {
  __shared__ unsigned short As[3 * 128 * 32];
  __shared__ unsigned short Bs[3 * 128 * 32];
  const int zz = blockIdx.z;
  const unsigned short* BT = (zz == 0) ? qwT : (zz == 1) ? kwT : vwT;
  unsigned short* Co = (zz == 0) ? Qo : (zz == 1) ? Ko : Vo;
  const int tid = threadIdx.x;
  const int l = tid & 63, w = tid >> 6;
  const int n0 = blockIdx.x * 128, m0 = blockIdx.y * 128;

  f32x4 acc[4][4];
#pragma unroll
  for (int i = 0; i < 4; ++i)
#pragma unroll
    for (int j = 0; j < 4; ++j) acc[i][j] = (f32x4){0.f, 0.f, 0.f, 0.f};

  gemm_loop<4, 4>(xbf, BT, As, Bs, acc, m0, n0, w, l);

  const int wr = w >> 1, wc = w & 1;
#pragma unroll
  for (int fm = 0; fm < 4; ++fm) {
#pragma unroll
    for (int fn = 0; fn < 4; ++fn) {
#pragma unroll
      for (int r = 0; r < 4; ++r) {
        float v = acc[fm][fn][r];
        int row = m0 + wr * 64 + fm * 16 + (l >> 4) * 4 + r;
        int col = n0 + wc * 64 + fn * 16 + (l & 15);
        if (zz < 2) {
          float p = __shfl_xor(v, 1);
          int t = row & (Tc - 1);
          int pi = (col & 63) >> 1;
          float cv = tabC[t * 32 + pi], sv = tabS[t * 32 + pi];
          float res = (col & 1) ? (p * sv + v * cv) : (v * cv - p * sv);
          Co[(size_t)row * Cc + col] = f2bf(phi_fn(res));
        } else {
          Co[(size_t)row * Cc + col] = f2bf(v);
        }
      }
    }
  }
}

// ---------------- out-proj: 64x128 tile, +bias +residual -> bf16 preO ----------------
__global__ __launch_bounds__(256) void k_oproj(const unsigned short* __restrict__ Ybf,
    const unsigned short* __restrict__ owT, unsigned short* __restrict__ Co,
    const float* __restrict__ bias, const float* __restrict__ resid) {
  __shared__ unsigned short As[3 * 64 * 32];
  __shared__ unsigned short Bs[3 * 128 * 32];
  const int tid = threadIdx.x;
  const int l = tid & 63, w = tid >> 6;
  const int n0 = blockIdx.x * 128, m0 = blockIdx.y * 64;

  f32x4 acc[2][4];
#pragma unroll
  for (int i = 0; i < 2; ++i)
#pragma unroll
    for (int j = 0; j < 4; ++j) acc[i][j] = (f32x4){0.f, 0.f, 0.f, 0.f};

  gemm_loop<2, 4>(Ybf, owT, As, Bs, acc, m0, n0, w, l);

  const int wr = w >> 1, wc = w & 1;
#pragma unroll
  for (int fm = 0; fm < 2; ++fm) {
#pragma unroll
    for (int fn = 0; fn < 4; ++fn) {
#pragma unroll
      for (int r = 0; r < 4; ++r) {
        int row = m0 + wr * 32 + fm * 16 + (l >> 4) * 4 + r;
        int col = n0 + wc * 64 + fn * 16 + (l & 15);
        Co[(size_t)row * Cc + col] = f2bf(acc[fm][fn][r] + bias[col] + resid[(size_t)row * Cc + col]);
      }
    }
  }
}

// ---------------- legacy fp32 SIMT GEMM (fallback path only) ----------------
template <typename AT, typename OT, int MODE>
__global__ __launch_bounds__(256) void k_gemm128(
    const AT* __restrict__ A, const float* __restrict__ Bw, OT* __restrict__ Co,
    int M, int N, int K,
    const float* __restrict__ tabC, const float* __restrict__ tabS,
    const float* __restrict__ bias, const float* __restrict__ resid) {
  __shared__ float As[16][132];
  __shared__ float Bs[16][132];
  const int tid = threadIdx.x;
  const int tx = tid & 15, ty = tid >> 4;
  const int n0 = blockIdx.x * 128, m0 = blockIdx.y * 128;
  float acc[8][8];
#pragma unroll
  for (int i = 0; i < 8; ++i)
#pragma unroll
    for (int j = 0; j < 8; ++j) acc[i][j] = 0.f;
  for (int k0 = 0; k0 < K; k0 += 16) {
#pragma unroll
    for (int rep = 0; rep < 2; ++rep) {
      int lin = tid + rep * 256;
      int r = lin >> 2, c4 = (lin & 3) << 2;
      float4 av = ld4(&A[(size_t)(m0 + r) * K + k0 + c4]);
      As[c4 + 0][r] = av.x; As[c4 + 1][r] = av.y;
      As[c4 + 2][r] = av.z; As[c4 + 3][r] = av.w;
      int rb = lin >> 5, cb = (lin & 31) << 2;
      *(float4*)&Bs[rb][cb] = *(const float4*)&Bw[(size_t)(k0 + rb) * N + n0 + cb];
    }
    __syncthreads();
#pragma unroll
    for (int kk = 0; kk < 16; ++kk) {
      float4 a0 = *(const float4*)&As[kk][ty * 8];
      float4 a1 = *(const float4*)&As[kk][ty * 8 + 4];
      float4 b0 = *(const float4*)&Bs[kk][tx * 8];
      float4 b1 = *(const float4*)&Bs[kk][tx * 8 + 4];
      float avv[8] = {a0.x, a0.y, a0.z, a0.w, a1.x, a1.y, a1.z, a1.w};
      float bvv[8] = {b0.x, b0.y, b0.z, b0.w, b1.x, b1.y, b1.z, b1.w};
#pragma unroll
      for (int i = 0; i < 8; ++i)
#pragma unroll
        for (int j = 0; j < 8; ++j) acc[i][j] = fmaf(avv[i], bvv[j], acc[i][j]);
    }
    __syncthreads();
  }
  if constexpr (MODE == 1) {
#pragma unroll
    for (int i = 0; i < 8; ++i) {
      int row = m0 + ty * 8 + i;
      int t = row & (Tc - 1);
#pragma unroll
      for (int j = 0; j < 8; j += 2) {
        int col = n0 + tx * 8 + j;
        int pi = (col & 63) >> 1;
        float cv = tabC[t * 32 + pi], sv = tabS[t * 32 + pi];
        float xe = acc[i][j], xo = acc[i][j + 1];
        stv(&Co[(size_t)row * N + col], phi_fn(xe * cv - xo * sv));
        stv(&Co[(size_t)row * N + col + 1], phi_fn(xe * sv + xo * cv));
      }
    }
  } else if constexpr (MODE == 2) {
#pragma unroll
    for (int i = 0; i < 8; ++i) {
      int row = m0 + ty * 8 + i;
#pragma unroll
      for (int j = 0; j < 8; ++j) {
        int col = n0 + tx * 8 + j;
        stv(&Co[(size_t)row * N + col], acc[i][j] + bias[col] + resid[(size_t)row * N + col]);
      }
    }
  } else {
#pragma unroll
    for (int i = 0; i < 8; ++i) {
      int row = m0 + ty * 8 + i;
#pragma unroll
      for (int j = 0; j < 8; ++j) {
        int col = n0 + tx * 8 + j;
        stv(&Co[(size_t)row * N + col], acc[i][j]);
      }
    }
  }
}

// ---------------- legacy k_small (fallback path only) ----------------
__global__ __launch_bounds__(256) void k_small(
    const float* __restrict__ x, const float* __restrict__ gate_w, const float* __restrict__ gate_b,
    const float* __restrict__ decay_w, const float* __restrict__ decay_b,
    const float* __restrict__ decay_w0, float* __restrict__ gate_o, float* __restrict__ rate_o,
    unsigned short* __restrict__ xbf_o) {
  __shared__ float xs[1024];
  __shared__ float part[8][32];
  int bt = blockIdx.x;
  int tid = threadIdx.x;
  float4 xv = *(const float4*)&x[(size_t)bt * Cc + tid * 4];
  *(float4*)&xs[tid * 4] = xv;
  if (xbf_o) {
    ushort4 u = make_ushort4(f2bf(xv.x), f2bf(xv.y), f2bf(xv.z), f2bf(xv.w));
    *(ushort4*)&xbf_o[(size_t)bt * Cc + tid * 4] = u;
  }
  __syncthreads();
  int o = tid & 31, seg = tid >> 5;
  const float* wp = (o < 16) ? gate_w : decay_w;
  int oc = o & 15;
  float p = 0.f;
  int kb = seg * 128;
#pragma unroll 4
  for (int kk = 0; kk < 128; ++kk) {
    int k = kb + kk;
    p = fmaf(xs[k], wp[(size_t)k * 16 + oc], p);
  }
  part[seg][o] = p;
  __syncthreads();
  if (tid < 32) {
    float s = 0.f;
#pragma unroll
    for (int sg = 0; sg < 8; ++sg) s += part[sg][tid];
    int b = bt >> 11, t = bt & (Tc - 1);
    if (tid < 16) {
      float gv = 1.f / (1.f + expf(-(s + gate_b[tid])));
      gate_o[((size_t)(b * Hc + tid)) * Tc + t] = gv;
    } else {
      int hh = tid - 16;
      float raw = s + decay_b[hh] + decay_w0[hh];
      float sp = raw > 20.f ? raw : log1pf(expf(raw));
      float rate = fminf(fmaxf(sp, 1e-4f), 10.f);
      rate_o[((size_t)(b * Hc + hh)) * Tc + t] = rate;
    }
  }
}

// ---------------- legacy k_tables / k_trans (fallback path only) ----------------
__global__ __launch_bounds__(256) void k_tables(float* __restrict__ tc, float* __restrict__ ts) {
  int i = blockIdx.x * 256 + threadIdx.x;
  int t = i >> 5, f = i & 31;
  float ivf = 1.0f / powf(10000.f, (float)f / 32.f);
  float fr = (float)t * ivf;
  tc[i] = cosf(fr);
  ts[i] = sinf(fr);
}

// ---------------- Phase A (MFMA): per-chunk summaries S^T[e][d], Dsum[d], P ----------------
__global__ __launch_bounds__(256) void k_scanA2(
    const unsigned short* __restrict__ Kb, const unsigned short* __restrict__ Vb,
    const float* __restrict__ rateB, const float* __restrict__ gateB,
    unsigned short* __restrict__ S, float* __restrict__ Dsum, float* __restrict__ Pbuf) {
  int blk = blockIdx.x;
  int bh = blk >> 5, c = blk & 31;
  int b = bh >> 4, h = bh & 15;
  int tid = threadIdx.x;
  int l = tid & 63, wv = tid >> 6;
  __shared__ unsigned short KT[64 * TP];   // [d][s]
  __shared__ unsigned short VT[64 * TP];   // [e][s], scaled by w_s
  __shared__ float Rc[64], gs[64], ws[64];
  size_t base = ((size_t)b * Tc + (size_t)c * 64) * Cc + h * 64;
  {
    int s = tid >> 2, d0g = (tid & 3) * 16;
    const unsigned short* kr = Kb + base + (size_t)s * Cc + d0g;
    unsigned short kv[16];
    *(uint4*)kv = *(const uint4*)kr; *(uint4*)(kv + 8) = *(const uint4*)(kr + 8);
#pragma unroll
    for (int i = 0; i < 16; ++i) KT[(d0g + i) * TP + s] = kv[i];
  }
  if (wv == 0) {
    float r = rateB[(size_t)bh * Tc + c * 64 + l];
    float g = gateB[(size_t)bh * Tc + c * 64 + l];
    float v = r;
#pragma unroll
    for (int off = 1; off < 64; off <<= 1) { float u = __shfl_up(v, off); if (l >= off) v += u; }
    Rc[l] = v; gs[l] = g;
  }
  __syncthreads();
  float Rtot = Rc[63];
  if (wv == 0) ws[l] = __expf(Rc[l] - Rtot) * gs[l];
  __syncthreads();
  {
    int s = tid >> 2, e0g = (tid & 3) * 16;
    float wsv = ws[s];
    const unsigned short* vr = Vb + base + (size_t)s * Cc + e0g;
    unsigned short vvv[16];
    *(uint4*)vvv = *(const uint4*)vr; *(uint4*)(vvv + 8) = *(const uint4*)(vr + 8);
#pragma unroll
    for (int i = 0; i < 16; ++i) VT[(e0g + i) * TP + s] = f2bf(bf2f(vvv[i]) * wsv);
  }
  __syncthreads();
  f32x4 acc[4];
#pragma unroll
  for (int i = 0; i < 4; ++i) acc[i] = (f32x4){0.f, 0.f, 0.f, 0.f};
  const int lrow = l & 15, lk8 = (l >> 4) * 8;
#pragma unroll
  for (int ks = 0; ks < 2; ++ks) {
    bf16x8 a = *(const bf16x8*)&VT[(wv * 16 + lrow) * TP + ks * 32 + lk8];
#pragma unroll
    for (int fn = 0; fn < 4; ++fn) {
      bf16x8 bb = *(const bf16x8*)&KT[(fn * 16 + lrow) * TP + ks * 32 + lk8];
      acc[fn] = __builtin_amdgcn_mfma_f32_16x16x32_bf16(a, bb, acc[fn], 0, 0, 0);
    }
  }
  size_t sb = (size_t)blk * 4096;
#pragma unroll
  for (int fn = 0; fn < 4; ++fn)
#pragma unroll
    for (int r = 0; r < 4; ++r) {
      int e = wv * 16 + (l >> 4) * 4 + r;
      int d = fn * 16 + (l & 15);
      S[sb + e * 64 + d] = f2bf(acc[fn][r]);
    }
  if (tid < 64) {
    float s = 0.f;
#pragma unroll 8
    for (int ss = 0; ss < 64; ++ss) s += bf2f(KT[tid * TP + ss]) * ws[ss];
    Dsum[(size_t)blk * 64 + tid] = s;
  }
  if (tid == 0) Pbuf[blk] = __expf(-Rtot);
}

// ---------------- Phase B: serial carry across chunks, element-partitioned (grid NBH*SBP) ----------------
__global__ __launch_bounds__(256) void k_scanB(unsigned short* __restrict__ S, float* __restrict__ Dsum,
                                               const float* __restrict__ Pbuf) {
  int blk = blockIdx.x;
  int bh = blk / SBP, part = blk % SBP;
  int tid = threadIdx.x;
  const int eo = part * 512 + tid;   // this block owns S elements [part*512, part*512+512)
  float N0 = 0.f, N1 = 0.f, Dreg = 0.f;
  const bool doD = (part == 0) && (tid < 64);
  unsigned short c0, c1; float cD = 0.f, cP;
  {
    size_t sb = ((size_t)bh * NCc) * 4096;
    c0 = S[sb + eo]; c1 = S[sb + eo + 256];
    if (doD) cD = Dsum[((size_t)bh * NCc) * 64 + tid];
    cP = Pbuf[bh * NCc];
  }
  for (int c = 0; c < NCc; ++c) {
    unsigned short n0s = 0, n1s = 0; float nD = 0.f, nP = 0.f;
    if (c + 1 < NCc) {
      size_t sb = ((size_t)bh * NCc + c + 1) * 4096;
      n0s = S[sb + eo]; n1s = S[sb + eo + 256];
      if (doD) nD = Dsum[((size_t)bh * NCc + c + 1) * 64 + tid];
      nP = Pbuf[bh * NCc + c + 1];
    }
    size_t sb = ((size_t)bh * NCc + c) * 4096;
    S[sb + eo] = f2bf(N0);
    S[sb + eo + 256] = f2bf(N1);
    N0 = N0 * cP + bf2f(c0);
    N1 = N1 * cP + bf2f(c1);
    if (doD) {
      Dsum[((size_t)bh * NCc + c) * 64 + tid] = Dreg;
      Dreg = Dreg * cP + cD;
    }
    c0 = n0s; c1 = n1s; cD = nD; cP = nP;
  }
}

// ---------------- Phase C (MFMA): intra-chunk + start-state, full output ----------------
__global__ __launch_bounds__(256) void k_scanC2(
    const unsigned short* __restrict__ Qb, const unsigned short* __restrict__ Kb,
    const unsigned short* __restrict__ Vb,
    const float* __restrict__ rateB, const float* __restrict__ gateB,
    const unsigned short* __restrict__ S, const float* __restrict__ Dsum,
    unsigned short* __restrict__ Yb) {
  int blk = blockIdx.x;
  int bh = blk >> 5, c = blk & 31;
  int b = bh >> 4, h = bh & 15;
  int tid = threadIdx.x;
  int l = tid & 63, wv = tid >> 6;
  __shared__ unsigned short Qs[64 * TP];
  __shared__ unsigned short Ks[64 * TP];   // overlaid by W' after QK
  __shared__ unsigned short VT[64 * TP];
  __shared__ unsigned short Ss[64 * TP];
  __shared__ float Rc[64], gs[64], DstL[64];
  size_t base = ((size_t)b * Tc + (size_t)c * 64) * Cc + h * 64;
  {
    int rr = tid >> 2, c0 = (tid & 3) * 16;
    const unsigned short* qr = Qb + base + (size_t)rr * Cc + c0;
    const unsigned short* kr = Kb + base + (size_t)rr * Cc + c0;
    const unsigned short* vr = Vb + base + (size_t)rr * Cc + c0;
    const unsigned short* sr = S + (size_t)blk * 4096 + rr * 64 + c0;
    *(uint4*)&Qs[rr * TP + c0] = *(const uint4*)qr;
    *(uint4*)&Qs[rr * TP + c0 + 8] = *(const uint4*)(qr + 8);
    *(uint4*)&Ks[rr * TP + c0] = *(const uint4*)kr;
    *(uint4*)&Ks[rr * TP + c0 + 8] = *(const uint4*)(kr + 8);
    *(uint4*)&Ss[rr * TP + c0] = *(const uint4*)sr;
    *(uint4*)&Ss[rr * TP + c0 + 8] = *(const uint4*)(sr + 8);
    unsigned short vvv[16];
    *(uint4*)vvv = *(const uint4*)vr; *(uint4*)(vvv + 8) = *(const uint4*)(vr + 8);
#pragma unroll
    for (int i = 0; i < 16; ++i) VT[(c0 + i) * TP + rr] = vvv[i];
  }
  if (wv == 0) {
    float r = rateB[(size_t)bh * Tc + c * 64 + l];
    float g = gateB[(size_t)bh * Tc + c * 64 + l];
    float v = r;
#pragma unroll
    for (int off = 1; off < 64; off <<= 1) { float u = __shfl_up(v, off); if (l >= off) v += u; }
    Rc[l] = v; gs[l] = g;
    DstL[l] = Dsum[(size_t)blk * 64 + l];
  }
  __syncthreads();
  const int lrow = l & 15, lk8 = (l >> 4) * 8;
  f32x4 qk[4];
#pragma unroll
  for (int i = 0; i < 4; ++i) qk[i] = (f32x4){0.f, 0.f, 0.f, 0.f};
#pragma unroll
  for (int ks = 0; ks < 2; ++ks) {
    bf16x8 a = *(const bf16x8*)&Qs[(wv * 16 + lrow) * TP + ks * 32 + lk8];
#pragma unroll
    for (int fn = 0; fn < 4; ++fn) {
      bf16x8 bb = *(const bf16x8*)&Ks[(fn * 16 + lrow) * TP + ks * 32 + lk8];
      qk[fn] = __builtin_amdgcn_mfma_f32_16x16x32_bf16(a, bb, qk[fn], 0, 0, 0);
    }
  }
  __syncthreads();
  float deni[4] = {0.f, 0.f, 0.f, 0.f};
  float rct[4];
#pragma unroll
  for (int r = 0; r < 4; ++r) rct[r] = Rc[wv * 16 + (l >> 4) * 4 + r];
#pragma unroll
  for (int fn = 0; fn < 4; ++fn) {
    int s = fn * 16 + (l & 15);
    float rs = Rc[s], g = gs[s];
#pragma unroll
    for (int r = 0; r < 4; ++r) {
      int t = wv * 16 + (l >> 4) * 4 + r;
      float wgt = (s <= t) ? __expf(rs - rct[r]) * g : 0.f;
      unsigned short sb16 = f2bf(qk[fn][r] * wgt);
      deni[r] += bf2f(sb16);
      Ks[t * TP + s] = sb16;
    }
  }
#pragma unroll
  for (int r = 0; r < 4; ++r) {
    deni[r] += __shfl_xor(deni[r], 1);
    deni[r] += __shfl_xor(deni[r], 2);
    deni[r] += __shfl_xor(deni[r], 4);
    deni[r] += __shfl_xor(deni[r], 8);
  }
  f32x4 nm[4], nm2[4], dn2;
#pragma unroll
  for (int i = 0; i < 4; ++i) { nm[i] = (f32x4){0.f,0.f,0.f,0.f}; nm2[i] = (f32x4){0.f,0.f,0.f,0.f}; }
  dn2 = (f32x4){0.f, 0.f, 0.f, 0.f};
#pragma unroll
  for (int ks = 0; ks < 2; ++ks) {
    bf16x8 aw = *(const bf16x8*)&Ks[(wv * 16 + lrow) * TP + ks * 32 + lk8];
    bf16x8 aq = *(const bf16x8*)&Qs[(wv * 16 + lrow) * TP + ks * 32 + lk8];
#pragma unroll
    for (int fn = 0; fn < 4; ++fn) {
      bf16x8 bv = *(const bf16x8*)&VT[(fn * 16 + lrow) * TP + ks * 32 + lk8];
      bf16x8 bs = *(const bf16x8*)&Ss[(fn * 16 + lrow) * TP + ks * 32 + lk8];
      nm[fn] = __builtin_amdgcn_mfma_f32_16x16x32_bf16(aw, bv, nm[fn], 0, 0, 0);
      nm2[fn] = __builtin_amdgcn_mfma_f32_16x16x32_bf16(aq, bs, nm2[fn], 0, 0, 0);
    }
    bf16x8 bd = (bf16x8){0, 0, 0, 0, 0, 0, 0, 0};
    if (lrow == 0) {
#pragma unroll
      for (int i = 0; i < 8; ++i) bd[i] = (short)f2bf(DstL[ks * 32 + lk8 + i]);
    }
    dn2 = __builtin_amdgcn_mfma_f32_16x16x32_bf16(aq, bd, dn2, 0, 0, 0);
  }
  float den2v[4];
#pragma unroll
  for (int r = 0; r < 4; ++r) den2v[r] = __shfl(dn2[r], (l & 48));
#pragma unroll
  for (int r = 0; r < 4; ++r) {
    int t = wv * 16 + (l >> 4) * 4 + r;
    float at = __expf(-rct[r]);
    float dv = deni[r] + at * den2v[r] + 1e-6f;
#pragma unroll
    for (int fn = 0; fn < 4; ++fn) {
      int e = fn * 16 + (l & 15);
      float numv = nm[fn][r] + at * nm2[fn][r];
      Yb[base + (size_t)t * Cc + e] = f2bf(numv / dv);
    }
  }
}

// ---------------- legacy serial scan (fallback path only; rate input) ----------------
__device__ __forceinline__ void load16(const unsigned short* __restrict__ p, float* d) {
  uint4 u = *(const uint4*)p;
  uint4 v = *(const uint4*)(p + 8);
  d[0] = __uint_as_float(u.x << 16); d[1] = __uint_as_float(u.x & 0xFFFF0000u);
  d[2] = __uint_as_float(u.y << 16); d[3] = __uint_as_float(u.y & 0xFFFF0000u);
  d[4] = __uint_as_float(u.z << 16); d[5] = __uint_as_float(u.z & 0xFFFF0000u);
  d[6] = __uint_as_float(u.w << 16); d[7] = __uint_as_float(u.w & 0xFFFF0000u);
  d[8] = __uint_as_float(v.x << 16); d[9] = __uint_as_float(v.x & 0xFFFF0000u);
  d[10] = __uint_as_float(v.y << 16); d[11] = __uint_as_float(v.y & 0xFFFF0000u);
  d[12] = __uint_as_float(v.z << 16); d[13] = __uint_as_float(v.z & 0xFFFF0000u);
  d[14] = __uint_as_float(v.w << 16); d[15] = __uint_as_float(v.w & 0xFFFF0000u);
}

__global__ __launch_bounds__(256) void k_scan(const unsigned short* __restrict__ phiQ,
    const unsigned short* __restrict__ phiK, const unsigned short* __restrict__ Vb,
    const float* __restrict__ rateB, const float* __restrict__ gateB,
    unsigned short* __restrict__ Yb) {
  int bh = blockIdx.x;
  int b = bh >> 4, h = bh & 15;
  int tid = threadIdx.x;
  int w = tid >> 6, l = tid & 63;
  int e = (w << 4) | (l & 15);
  int d0 = (l >> 4) << 4;
  size_t base = ((size_t)b * Tc) * Cc + h * 64;
  const unsigned short* qp = phiQ + base + d0;
  const unsigned short* kp = phiK + base + d0;
  const unsigned short* vp = Vb + base + e;
  const float* bp = rateB + (size_t)bh * Tc;
  const float* gp = gateB + (size_t)bh * Tc;
  unsigned short* yp = Yb + base + e;
  float Ns[16], Ds[16];
#pragma unroll
  for (int j = 0; j < 16; ++j) { Ns[j] = 0.f; Ds[j] = 0.f; }
  const bool wr = (l < 16);
  for (int t = 0; t < Tc; ++t) {
    float q[16], k[16];
    load16(qp + (size_t)t * Cc, q);
    load16(kp + (size_t)t * Cc, k);
    float vv = bf2f(vp[(size_t)t * Cc]);
    float btv = __expf(-bp[t]), gtv = gp[t];
    float yn = 0.f, den = 0.f;
#pragma unroll
    for (int j = 0; j < 16; ++j) {
      float wj = k[j] * gtv;
      float ns = fmaf(Ns[j], btv, wj * vv);
      float ds = fmaf(Ds[j], btv, wj);
      Ns[j] = ns; Ds[j] = ds;
      yn = fmaf(q[j], ns, yn);
      den = fmaf(q[j], ds, den);
    }
    yn += __shfl_xor(yn, 16); yn += __shfl_xor(yn, 32);
    den += __shfl_xor(den, 16); den += __shfl_xor(den, 32);
    if (wr) yp[(size_t)t * Cc] = f2bf(yn / (den + 1e-6f));
  }
}

// ---------------- row LayerNorm -> fp32 out (templated input) ----------------
template <typename PT>
__global__ __launch_bounds__(256) void k_ln(const PT* __restrict__ pre, const float* __restrict__ ln_g,
    const float* __restrict__ ln_b, float* __restrict__ out) {
  int row = blockIdx.x;
  int tid = threadIdx.x;
  float4 v = ld4(&pre[(size_t)row * Cc + tid * 4]);
  float s = v.x + v.y + v.z + v.w;
  float q = v.x * v.x + v.y * v.y + v.z * v.z + v.w * v.w;
#pragma unroll
  for (int off = 1; off < 64; off <<= 1) {
    s += __shfl_xor(s, off);
    q += __shfl_xor(q, off);
  }
  __shared__ float ss[4], qq[4];
  if ((tid & 63) == 0) { ss[tid >> 6] = s; qq[tid >> 6] = q; }
  __syncthreads();
  s = ss[0] + ss[1] + ss[2] + ss[3];
  q = qq[0] + qq[1] + qq[2] + qq[3];
  float mu = s * (1.f / 1024.f);
  float var = q * (1.f / 1024.f) - mu * mu;
  float rstd = rsqrtf(var + 1e-5f);
  int c0 = tid * 4;
  float4 g = *(const float4*)&ln_g[c0];
  float4 bb = *(const float4*)&ln_b[c0];
  float4 o;
  o.x = (v.x - mu) * rstd * g.x + bb.x;
  o.y = (v.y - mu) * rstd * g.y + bb.y;
  o.z = (v.z - mu) * rstd * g.z + bb.z;
  o.w = (v.w - mu) * rstd * g.w + bb.w;
  *(float4*)&out[(size_t)row * Cc + c0] = o;
}

extern "C" void kernel_launch(void* const* d_in, const int* in_sizes, int n_in,
                              void* d_out, int out_size, void* d_ws, size_t ws_size,
                              hipStream_t stream) {
  const float* x        = (const float*)d_in[0];
  const float* q_w      = (const float*)d_in[1];
  const float* k_w      = (const float*)d_in[2];
  const float* v_w      = (const float*)d_in[3];
  const float* out_w    = (const float*)d_in[4];
  const float* out_b    = (const float*)d_in[5];
  const float* decay_w  = (const float*)d_in[6];
  const float* decay_b  = (const float*)d_in[7];
  const float* gate_w   = (const float*)d_in[8];
  const float* gate_b   = (const float*)d_in[9];
  const float* decay_w0 = (const float*)d_in[10];
  const float* ln_g     = (const float*)d_in[11];
  const float* ln_b     = (const float*)d_in[12];
  float* out            = (float*)d_out;

  const size_t MC  = (size_t)Mc * Cc;
  const size_t BHT = (size_t)Bc * Hc * Tc;
  const int NBH = Bc * Hc;                 // 32

  const bool fp32path = ws_size >= (size_t)52 * 1024 * 1024;

  if (fp32path) {
    char* p = (char*)d_ws;
    float* tabC = (float*)p;                    p += (size_t)Tc * 32 * 4;
    float* tabS = (float*)p;                    p += (size_t)Tc * 32 * 4;
    unsigned short* xbf   = (unsigned short*)p; p += MC * 2;        // S aliases (8 MiB)
    unsigned short* qwT   = (unsigned short*)p; p += (size_t)Cc * Cc * 2;
    unsigned short* kwT   = (unsigned short*)p; p += (size_t)Cc * Cc * 2;
    unsigned short* vwT   = (unsigned short*)p; p += (size_t)Cc * Cc * 2;
    unsigned short* owT   = (unsigned short*)p; p += (size_t)Cc * Cc * 2;
    unsigned short* phiQb = (unsigned short*)p; p += MC * 2;        // preO (bf16) overlays phiQb
    unsigned short* Vbf   = (unsigned short*)p; p += MC * 2;
    unsigned short* phiKb = (unsigned short*)p; p += MC * 2;
    unsigned short* Ybf   = (unsigned short*)p; p += MC * 2;
    float* rateB = (float*)p;                   p += BHT * 4;
    float* gateB = (float*)p;                   p += BHT * 4;
    float* Dsum  = (float*)p;                   p += (size_t)NBH * NCc * 64 * 4;
    float* Pbuf  = (float*)p;                   p += (size_t)NBH * NCc * 4;
    unsigned short* S = xbf;                    // xbf dead after projection GEMMs
    unsigned short* preO = phiQb;               // phiQb dead after scanC2

    k_pre<<<2 * Mc + (Tc * 32) / 256, 256, 0, stream>>>(
        x, gate_w, gate_b, decay_w, decay_b, decay_w0, gateB, rateB, xbf,
        q_w, k_w, v_w, out_w, qwT, kwT, vwT, owT, tabC, tabS);

    k_qkv<<<dim3(Cc / 128, Mc / 128, 3), 256, 0, stream>>>(xbf, qwT, kwT, vwT,
                                                           phiQb, phiKb, Vbf, tabC, tabS);

    k_scanA2<<<NBH * NCc, 256, 0, stream>>>(phiKb, Vbf, rateB, gateB, S, Dsum, Pbuf);
    k_scanB<<<NBH * SBP, 256, 0, stream>>>(S, Dsum, Pbuf);
    k_scanC2<<<NBH * NCc, 256, 0, stream>>>(phiQb, phiKb, Vbf, rateB, gateB, S, Dsum, Ybf);

    k_oproj<<<dim3(Cc / 128, Mc / 64), 256, 0, stream>>>(Ybf, owT, preO, out_b, x);
    k_ln<unsigned short><<<Mc, 256, 0, stream>>>(preO, ln_g, ln_b, out);
  } else {
    // ---- 33 MiB bf16-intermediate fallback (serial scan, SIMT GEMM) ----
    float* tabC  = (float*)d_ws;
    float* tabS  = tabC + (size_t)Tc * 32;
    unsigned short* phiQb = (unsigned short*)(tabS + (size_t)Tc * 32);
    unsigned short* phiKb = phiQb + MC;
    unsigned short* Vbb   = phiKb + MC;
    unsigned short* Ybb   = Vbb + MC;
    float* rateB = (float*)(Ybb + MC);
    float* gateB = rateB + BHT;
    float* preO  = (float*)phiQb;
    dim3 gg(Cc / 128, Mc / 128);

    k_tables<<<(Tc * 32) / 256, 256, 0, stream>>>(tabC, tabS);
    k_gemm128<float, unsigned short, 1><<<gg, 256, 0, stream>>>(x, q_w, phiQb, Mc, Cc, Cc, tabC, tabS, nullptr, nullptr);
    k_gemm128<float, unsigned short, 1><<<gg, 256, 0, stream>>>(x, k_w, phiKb, Mc, Cc, Cc, tabC, tabS, nullptr, nullptr);
    k_gemm128<float, unsigned short, 0><<<gg, 256, 0, stream>>>(x, v_w, Vbb, Mc, Cc, Cc, nullptr, nullptr, nullptr, nullptr);
    k_small<<<Mc, 256, 0, stream>>>(x, gate_w, gate_b, decay_w, decay_b, decay_w0, gateB, rateB, nullptr);
    k_scan<<<Bc * Hc, 256, 0, stream>>>(phiQb, phiKb, Vbb, rateB, gateB, Ybb);
    k_gemm128<unsigned short, float, 2><<<gg, 256, 0, stream>>>(Ybb, out_w, preO, Mc, Cc, Cc, nullptr, nullptr, out_b, x);
    k_ln<float><<<Mc, 256, 0, stream>>>(preO, ln_g, ln_b, out);
  }
}